// Round 12
// baseline (553.584 us; speedup 1.0000x reference)
//
#include <hip/hip_runtime.h>
#include <hip/hip_fp16.h>
#include <math.h>

#define D128 128   // H*Ch
#define CH32 32
#define CE16 16

// ---------------- CSR build ----------------
__global__ void k_hist(const int* __restrict__ dst, int* __restrict__ deg, int E) {
    int e = blockIdx.x * blockDim.x + threadIdx.x;
    if (e < E) atomicAdd(&deg[dst[e]], 1);
}

__global__ void k_scan1(const int* __restrict__ deg, int* __restrict__ offs,
                        int* __restrict__ bsum, int N) {
    __shared__ int buf[256];
    int t = threadIdx.x;
    int i = blockIdx.x * 256 + t;
    int v = (i < N) ? deg[i] : 0;
    buf[t] = v;
    __syncthreads();
    #pragma unroll
    for (int off = 1; off < 256; off <<= 1) {
        int val = (t >= off) ? buf[t - off] : 0;
        __syncthreads();
        buf[t] += val;
        __syncthreads();
    }
    if (i < N) offs[i] = buf[t] - v;
    if (t == 255) bsum[blockIdx.x] = buf[255];
}

__global__ void k_scan2(const int* __restrict__ bsum, int* __restrict__ boff, int nb) {
    // requires nb <= 256 (N <= 65536)
    __shared__ int buf[256];
    int t = threadIdx.x;
    int v = (t < nb) ? bsum[t] : 0;
    buf[t] = v;
    __syncthreads();
    #pragma unroll
    for (int off = 1; off < 256; off <<= 1) {
        int val = (t >= off) ? buf[t - off] : 0;
        __syncthreads();
        buf[t] += val;
        __syncthreads();
    }
    if (t < nb) boff[t] = buf[t] - v;
}

__global__ void k_scan3(const int* __restrict__ boff, int* __restrict__ offs,
                        int* __restrict__ cur, int N, int E) {
    int i = blockIdx.x * blockDim.x + threadIdx.x;
    if (i < N) {
        int o = offs[i] + boff[i >> 8];
        offs[i] = o;
        cur[i] = o;
    }
    if (i == 0) offs[N] = E;
}

// ---------------- CSR scatter (R12: indices only, packed) ----------------
// R11 removed the write-amplified ea permutation by splitting; R12 removes the
// ea permutation ENTIRELY: edgeattn reads ea directly via eid (random 64B
// granule, L3-resident — same latency class its kv pipeline already hides),
// and k_mlp runs in original edge order (ea/src/dst/out all streams).
// Scattered writes here: one packed int2 {src<<9, eid<<6} per edge (9.6MB).
__global__ void k_scatter_idx(const int* __restrict__ src, const int* __restrict__ dst,
                              int* __restrict__ cur, int2* __restrict__ csr_se, int E) {
    int e = blockIdx.x * blockDim.x + threadIdx.x;
    if (e < E) {
        int d = dst[e];
        int p = atomicAdd(&cur[d], 1);
        csr_se[p] = make_int2(src[e] << 9,   // byte offset into fp16 kv rows (512B)
                              e << 6);       // byte offset into ea rows (64B)
    }
}

// ---------------- Wqe = QS * (Wq_h . We_h^T) + bias, both layers, parallel ------
// 66 blocks x 64 threads (layer x row; row 32 = bias), 32 FMA/thread.
__global__ void k_wqe(const float* __restrict__ Wq1, const float* __restrict__ bq1,
                      const float* __restrict__ We1,
                      const float* __restrict__ Wq2, const float* __restrict__ bq2,
                      const float* __restrict__ We2,
                      float* __restrict__ Wqe1, float* __restrict__ bqe1,
                      float* __restrict__ Wqe2, float* __restrict__ bqe2) {
    int t = threadIdx.x, h = t >> 4, j = t & 15;
    const float QS = 0.17677669529663687f * 1.4426950408889634f;
    int b = blockIdx.x;              // 0..65
    int layer = (b >= 33);
    int i = layer ? b - 33 : b;      // 0..32 (32 = bias row)
    const float* Wq = layer ? Wq2 : Wq1;
    const float* bq = layer ? bq2 : bq1;
    const float* We = layer ? We2 : We1;
    float* Wqe = layer ? Wqe2 : Wqe1;
    float* bqe = layer ? bqe2 : bqe1;
    const float* base = (i < 32) ? (Wq + i * D128) : bq;
    float s = 0.f;
    #pragma unroll
    for (int d = 0; d < 32; d++)
        s = fmaf(base[h * 32 + d], We[j * D128 + h * 32 + d], s);
    s *= QS;
    if (i < 32) Wqe[i * 64 + t] = s;
    else        bqe[t] = s;
}

// ---------------- node projection: q + fp16 kv + skip + qeb (fused) -------------
// kv row layout (256 halves = 512 B): per 4-channel group c=ch>>2:
//   halves[8c+0..8c+3] = k[4c..4c+3], halves[8c+4..8c+7] = v[4c..4c+3]
__global__ __launch_bounds__(128) void k_nodeproj(
    const float* __restrict__ xin,
    const float* __restrict__ Wq, const float* __restrict__ bq,
    const float* __restrict__ Wk, const float* __restrict__ bk,
    const float* __restrict__ Wv, const float* __restrict__ bv,
    const float* __restrict__ Ws, const float* __restrict__ bs,
    const float* __restrict__ Wqe, const float* __restrict__ bqe,
    float* __restrict__ q, __half* __restrict__ kvh,
    float* __restrict__ skip, float* __restrict__ qeb, int N)
{
    int tid = threadIdx.x;      // 0..127: output column of q/k/v
    int c   = tid & 31;         // output column of skip
    int pos = ((tid >> 2) << 3) | (tid & 3);   // k half-position; v at pos+4
    float wq[32], wk[32], wv[32], ws[32];
    #pragma unroll
    for (int j = 0; j < 32; j++) {
        wq[j] = Wq[j * D128 + tid];
        wk[j] = Wk[j * D128 + tid];
        wv[j] = Wv[j * D128 + tid];
        ws[j] = Ws[j * CH32 + c];
    }
    float bqc = bq[tid], bkc = bk[tid], bvc = bv[tid], bsc = bs[c];
    __shared__ float wqeS[32][64];   // 8 KB
    __shared__ float xs[4][32];
    for (int i = tid; i < 2048; i += 128) wqeS[i >> 6][i & 63] = Wqe[i];
    float bqec = bqe[tid & 63];
    int nchunk = (N + 3) / 4;
    for (int chk = blockIdx.x; chk < nchunk; chk += gridDim.x) {
        int base = chk * 4;
        {
            int r = tid >> 5;
            int n = base + r;
            xs[r][c] = (n < N) ? xin[n * 32 + c] : 0.f;
        }
        __syncthreads();
        #pragma unroll
        for (int r = 0; r < 4; r++) {
            int n = base + r;
            if (n < N) {
                float aq = bqc, ak = bkc, av = bvc;
                #pragma unroll
                for (int j = 0; j < 32; j++) {
                    float xj = xs[r][j];
                    aq = fmaf(xj, wq[j], aq);
                    ak = fmaf(xj, wk[j], ak);
                    av = fmaf(xj, wv[j], av);
                }
                q[n * D128 + tid] = aq;
                kvh[(size_t)n * 256 + pos]     = __float2half_rn(ak);  // k
                kvh[(size_t)n * 256 + pos + 4] = __float2half_rn(av);  // v
            }
        }
        {
            int r = tid >> 5;
            int n = base + r;
            if (n < N) {
                float as = bsc;
                #pragma unroll
                for (int j = 0; j < 32; j++) as = fmaf(xs[r][j], ws[j], as);
                skip[n * 32 + c] = as;
            }
        }
        {   // qeb: thread (half,c6) covers nodes {2*half, 2*half+1}, col c6
            int c6 = tid & 63;
            int r0 = (tid >> 6) << 1;
            #pragma unroll
            for (int rr = 0; rr < 2; rr++) {
                int n = base + r0 + rr;
                if (n < N) {
                    float a = bqec;
                    #pragma unroll
                    for (int j = 0; j < 32; j++)
                        a = fmaf(xs[r0 + rr][j], wqeS[j][c6], a);
                    qeb[(size_t)n * 64 + c6] = a;
                }
            }
        }
        __syncthreads();
    }
}

// ---------------- edge attention: one WAVE per node, 2 EDGES per VMEM instr -----
// Verified R9 structure: lane owns 4 channels, 32 lanes/edge, 2 edges per VMEM
// instr, ping-pong pipeline, fp16 kv, precomputed qe. R12: ea read DIRECTLY via
// eid byte-offset (csr_se.y) — one random 64B granule per edge, L3-resident,
// hidden by the same one-phase-ahead prefetch as kv. No ea_csr buffer.
// Algebra (validated R3): alpha = q.k[src] + qe.ea ; out = (sum p*v)/l +
// We^T(sum p*ea)/l. No-max softmax: logits provably tiny (weight scale 0.05).
__global__ __launch_bounds__(64) void k_edgeattn(
    const float* __restrict__ q, const __half* __restrict__ kvh,
    const float* __restrict__ skip,
    const float* __restrict__ ea, const float* __restrict__ We,
    const int* __restrict__ offs, const int2* __restrict__ csr_se,
    const float* __restrict__ qeb, float* __restrict__ hout)
{
    int node = blockIdx.x;
    int lane = threadIdx.x;        // 0..63
    int eg   = lane >> 5;          // which edge of the pair this half handles
    int c    = lane & 31;          // 4-channel group; head = c>>3
    int g    = c & 7;              // lane within 8-lane head group
    int c4   = c << 2;             // first owned channel

    // q pre-scaled by 1/sqrt(32) * log2(e)  (exp(x) == exp2(x*log2e))
    const float QS = 0.17677669529663687f * 1.4426950408889634f;
    float4 qv = *(const float4*)&q[(size_t)node * D128 + c4];
    qv.x *= QS; qv.y *= QS; qv.z *= QS; qv.w *= QS;

    // qe dims 2g, 2g+1 of this lane's head: precomputed (QS folded in k_wqe)
    float2 qe01 = *(const float2*)&qeb[(size_t)node * 64 + ((c >> 3) << 4) + 2 * g];
    float qe0 = qe01.x, qe1 = qe01.y;

    int s0 = offs[node], s1 = offs[node + 1];
    int deg = s1 - s0;

    float l = 0.f;
    float ac0 = 0.f, ac1 = 0.f, ac2 = 0.f, ac3 = 0.f;
    float se0 = 0.f, se1 = 0.f;

    if (deg > 0) {
        int last = s1 - 1;
        const char* kvb = (const char*)kvh;
        const char* eab = (const char*)ea;
        int toff = c << 4;           // 16 bytes per 4-channel group
        int goff = g << 3;           // 8 bytes per g within the 64B ea row

        // lane's edge for pair-slot p: e = s0 + 2p + eg (clamped to last)
        auto ldse = [&](int p) { return csr_se[min(s0 + 2 * p + eg, last)]; };
        auto ldkv = [&](int ib) {
            return *(const float4*)(kvb + (size_t)(unsigned)ib + toff);
        };
        auto ldea = [&](int ib) {
            return *(const float2*)(eab + (size_t)(unsigned)ib + goff);
        };
        auto pair = [&](const float4& kvr, const float2& eav, int p) {
            bool valid = (s0 + 2 * p + eg) <= last;
            float2 k01 = __half22float2(*(const __half2*)&kvr.x);
            float2 k23 = __half22float2(*(const __half2*)&kvr.y);
            float2 v01 = __half22float2(*(const __half2*)&kvr.z);
            float2 v23 = __half22float2(*(const __half2*)&kvr.w);
            float t = fmaf(qv.y, k01.y, qv.x * k01.x);
            t = fmaf(qv.z, k23.x, t);
            t = fmaf(qv.w, k23.y, t);
            t = fmaf(qe0, eav.x, t);
            t = fmaf(qe1, eav.y, t);
            t += __shfl_xor(t, 1);
            t += __shfl_xor(t, 2);
            t += __shfl_xor(t, 4);
            float pp = valid ? __builtin_amdgcn_exp2f(t) : 0.f;
            l += pp;
            ac0 = fmaf(pp, v01.x, ac0);
            ac1 = fmaf(pp, v01.y, ac1);
            ac2 = fmaf(pp, v23.x, ac2);
            ac3 = fmaf(pp, v23.y, ac3);
            se0 = fmaf(pp, eav.x, se0);
            se1 = fmaf(pp, eav.y, se1);
        };

        // prologue: packed idx for pair-slots 0,1 (A) and 2,3 (B); kv/ea for A
        int2 iA0 = ldse(0), iA1 = ldse(1);
        int2 iB0 = ldse(2), iB1 = ldse(3);
        float4 kA0 = ldkv(iA0.x), kA1 = ldkv(iA1.x);
        float2 eA0 = ldea(iA0.y), eA1 = ldea(iA1.y);

        int p = 0;
        int nIter = (deg + 7) >> 3;     // 8 edges = 4 pair-slots per iteration
        for (int it = 0; it < nIter; ++it) {
            // issue phase-B loads (pair-slots p+2, p+3)
            float4 kB0 = ldkv(iB0.x), kB1 = ldkv(iB1.x);
            float2 eB0 = ldea(iB0.y), eB1 = ldea(iB1.y);
            // prefetch packed indices for next phase A (slots p+4, p+5)
            iA0 = ldse(p + 4); iA1 = ldse(p + 5);

            // compute phase A (kv/ea issued one phase ago)
            pair(kA0, eA0, p + 0);
            pair(kA1, eA1, p + 1);

            // issue next phase-A loads (slots p+4, p+5)
            kA0 = ldkv(iA0.x); kA1 = ldkv(iA1.x);
            eA0 = ldea(iA0.y); eA1 = ldea(iA1.y);
            // prefetch packed indices for next phase B (slots p+6, p+7)
            iB0 = ldse(p + 6); iB1 = ldse(p + 7);

            // compute phase B
            pair(kB0, eB0, p + 2);
            pair(kB1, eB1, p + 3);

            p += 4;
        }
    }

    // epilogue: combine the two edge-halves, normalize, project sea through We,
    // mean over 4 heads, add skip, relu, store.
    l   += __shfl_xor(l, 32);
    ac0 += __shfl_xor(ac0, 32);
    ac1 += __shfl_xor(ac1, 32);
    ac2 += __shfl_xor(ac2, 32);
    ac3 += __shfl_xor(ac3, 32);
    se0 += __shfl_xor(se0, 32);
    se1 += __shfl_xor(se1, 32);

    float inv = 1.0f / (l + 1e-16f);
    float r0 = ac0 * inv, r1 = ac1 * inv, r2 = ac2 * inv, r3 = ac3 * inv;
    float sn0 = se0 * inv, sn1 = se1 * inv;

    int gb = lane & ~7;              // base lane of this 8-lane head group
    #pragma unroll
    for (int j = 0; j < 16; j++) {
        float sj = __shfl((j & 1) ? sn1 : sn0, gb | (j >> 1), 64);
        float4 wj = *(const float4*)&We[j * D128 + c4];
        r0 = fmaf(sj, wj.x, r0);
        r1 = fmaf(sj, wj.y, r1);
        r2 = fmaf(sj, wj.z, r2);
        r3 = fmaf(sj, wj.w, r3);
    }
    // head mean: lanes c, c^8, c^16, c^24 hold the same output dims for the 4 heads
    r0 += __shfl_xor(r0, 8);  r0 += __shfl_xor(r0, 16);
    r1 += __shfl_xor(r1, 8);  r1 += __shfl_xor(r1, 16);
    r2 += __shfl_xor(r2, 8);  r2 += __shfl_xor(r2, 16);
    r3 += __shfl_xor(r3, 8);  r3 += __shfl_xor(r3, 16);
    if (lane < 8) {
        const float4 sk = *(const float4*)&skip[(size_t)node * 32 + c4];
        float4 o;
        o.x = fmaxf(fmaf(0.25f, r0, sk.x), 0.f);
        o.y = fmaxf(fmaf(0.25f, r1, sk.y), 0.f);
        o.z = fmaxf(fmaf(0.25f, r2, sk.z), 0.f);
        o.w = fmaxf(fmaf(0.25f, r3, sk.w), 0.f);
        *(float4*)&hout[(size_t)node * 32 + c4] = o;
    }
}

// ---------------- hA = h@A + bm1, hC = h@C (per-node MLP pre-projection) --------
// Wm1 is [80][32]: A = rows 0..31 (h[src]), B = rows 32..47 (ea), C = rows 48..79
// (h[dst]). 80% of k_mlp's GEMM is per-NODE work repeated per edge -> hoist it.
__global__ __launch_bounds__(256) void k_postproj(
    const float* __restrict__ h, const float* __restrict__ Wm1,
    const float* __restrict__ bm1, float* __restrict__ hA,
    float* __restrict__ hC, int N) {
    __shared__ float WA[32][32], WC[32][32];   // 8 KB
    __shared__ float hs[8][32];
    int tid = threadIdx.x;
    for (int i = tid; i < 1024; i += 256) {
        WA[i >> 5][i & 31] = Wm1[i];                 // rows 0..31
        WC[i >> 5][i & 31] = Wm1[48 * 32 + i];       // rows 48..79
    }
    int col = tid & 31, r = tid >> 5;    // 8 nodes x 32 cols
    float bb = bm1[col];
    __syncthreads();
    int nchunk = (N + 7) / 8;
    for (int chk = blockIdx.x; chk < nchunk; chk += gridDim.x) {
        int n = chk * 8 + r;
        hs[r][col] = (n < N) ? h[(size_t)n * 32 + col] : 0.f;
        __syncthreads();
        if (n < N) {
            float a = bb, cc = 0.f;
            #pragma unroll
            for (int j = 0; j < 32; j++) {
                float hj = hs[r][j];
                a  = fmaf(hj, WA[j][col], a);
                cc = fmaf(hj, WC[j][col], cc);
            }
            hA[(size_t)n * 32 + col] = a;
            hC[(size_t)n * 32 + col] = cc;
        }
        __syncthreads();
    }
}

// ---------------- edge MLP: original edge order (R12) ----------------------------
// src/dst/ea are perfect streams; out[e] sequential write; hA[src]/hC[dst] are
// random 128B gathers into 6.4MB L2-resident tables. No CSR arrays needed.
__global__ __launch_bounds__(256) void k_mlp(
    const float* __restrict__ hA, const float* __restrict__ hC,
    const float* __restrict__ ea,
    const int* __restrict__ src, const int* __restrict__ dst,
    const float* __restrict__ Wm1, const float* __restrict__ Wm2,
    const float* __restrict__ bm2, float* __restrict__ out, int E)
{
    __shared__ float4 B4[16 * 8];     // Wm1 rows 32..47 as float4
    __shared__ float wm2L[32];
    int tid = threadIdx.x;
    const float4* Wm1B = (const float4*)(Wm1 + 32 * 32);
    for (int i = tid; i < 128; i += 256) B4[i] = Wm1B[i];
    if (tid < 32) wm2L[tid] = Wm2[tid];
    __syncthreads();

    int e = blockIdx.x * 256 + tid;
    if (e >= E) return;
    float b2 = bm2[0];
    int s = src[e], d = dst[e];

    const float4* pa  = (const float4*)(hA + (size_t)s * 32);
    const float4* pc  = (const float4*)(hC + (size_t)d * 32);
    const float4* eav = (const float4*)(ea + (size_t)e * 16);

    float4 acc[8];
    #pragma unroll
    for (int i = 0; i < 8; i++) {
        float4 va = pa[i], vc = pc[i];
        acc[i] = make_float4(va.x + vc.x, va.y + vc.y, va.z + vc.z, va.w + vc.w);
    }

    auto dorow = [&](int j, float xj) {
        #pragma unroll
        for (int c4 = 0; c4 < 8; c4++) {
            float4 w = B4[j * 8 + c4];
            acc[c4].x = fmaf(xj, w.x, acc[c4].x);
            acc[c4].y = fmaf(xj, w.y, acc[c4].y);
            acc[c4].z = fmaf(xj, w.z, acc[c4].z);
            acc[c4].w = fmaf(xj, w.w, acc[c4].w);
        }
    };

    #pragma unroll
    for (int qd = 0; qd < 4; qd++) {   // B rows 0..15: edge_attr
        float4 xv = eav[qd];
        dorow(qd * 4 + 0, xv.x); dorow(qd * 4 + 1, xv.y);
        dorow(qd * 4 + 2, xv.z); dorow(qd * 4 + 3, xv.w);
    }

    float y = b2;
    #pragma unroll
    for (int c4 = 0; c4 < 8; c4++) {
        y += fmaxf(acc[c4].x, 0.f) * wm2L[c4 * 4 + 0];
        y += fmaxf(acc[c4].y, 0.f) * wm2L[c4 * 4 + 1];
        y += fmaxf(acc[c4].z, 0.f) * wm2L[c4 * 4 + 2];
        y += fmaxf(acc[c4].w, 0.f) * wm2L[c4 * 4 + 3];
    }
    out[e] = y;
}

extern "C" void kernel_launch(void* const* d_in, const int* in_sizes, int n_in,
                              void* d_out, int out_size, void* d_ws, size_t ws_size,
                              hipStream_t stream)
{
    const float* x  = (const float*)d_in[0];
    const float* ea = (const float*)d_in[1];
    const int*   ei = (const int*)d_in[2];
    const int N = in_sizes[0] / 32;
    const int E = in_sizes[1] / 16;
    const int* src = ei;
    const int* dst = ei + E;

    const float *Wq1 = (const float*)d_in[3],  *bq1 = (const float*)d_in[4];
    const float *Wk1 = (const float*)d_in[5],  *bk1 = (const float*)d_in[6];
    const float *Wv1 = (const float*)d_in[7],  *bv1 = (const float*)d_in[8];
    const float *We1 = (const float*)d_in[9],  *Ws1 = (const float*)d_in[10];
    const float *bs1 = (const float*)d_in[11];
    const float *Wq2 = (const float*)d_in[12], *bq2 = (const float*)d_in[13];
    const float *Wk2 = (const float*)d_in[14], *bk2 = (const float*)d_in[15];
    const float *Wv2 = (const float*)d_in[16], *bv2 = (const float*)d_in[17];
    const float *We2 = (const float*)d_in[18], *Ws2 = (const float*)d_in[19];
    const float *bs2 = (const float*)d_in[20];
    const float *Wm1 = (const float*)d_in[21], *bm1 = (const float*)d_in[22];
    const float *Wm2 = (const float*)d_in[23], *bm2 = (const float*)d_in[24];

    char* w = (char*)d_ws;
    auto alloc = [&](size_t bytes) -> void* {
        void* p = (void*)w;
        w += (bytes + 255) & ~(size_t)255;
        return p;
    };
    int* deg      = (int*)alloc((size_t)N * 4);
    int* offs     = (int*)alloc(((size_t)N + 1) * 4);
    int* cur      = (int*)alloc((size_t)N * 4);
    int* bsum     = (int*)alloc(256 * 4);
    int* boff     = (int*)alloc(256 * 4);
    int2* csr_se  = (int2*)alloc((size_t)E * 8);
    float* qb     = (float*)alloc((size_t)N * 128 * 4);
    __half* kvb   = (__half*)alloc((size_t)N * 256 * 2);
    float* skipb  = (float*)alloc((size_t)N * 32 * 4);
    float* h1     = (float*)alloc((size_t)N * 32 * 4);
    float* h2     = (float*)alloc((size_t)N * 32 * 4);
    float* Wqe1   = (float*)alloc(32 * 64 * 4);
    float* bqe1   = (float*)alloc(64 * 4);
    float* Wqe2   = (float*)alloc(32 * 64 * 4);
    float* bqe2   = (float*)alloc(64 * 4);
    float* qeb    = (float*)alloc((size_t)N * 64 * 4);
    float* hA     = (float*)alloc((size_t)N * 32 * 4);
    float* hC     = (float*)alloc((size_t)N * 32 * 4);

    hipMemsetAsync(deg, 0, (size_t)N * 4, stream);

    int ebl = (E + 255) / 256;
    int nb  = (N + 255) / 256;   // <= 256 required by k_scan2
    k_wqe<<<66, 64, 0, stream>>>(Wq1, bq1, We1, Wq2, bq2, We2,
                                 Wqe1, bqe1, Wqe2, bqe2);
    k_hist<<<ebl, 256, 0, stream>>>(dst, deg, E);
    k_scan1<<<nb, 256, 0, stream>>>(deg, offs, bsum, N);
    k_scan2<<<1, 256, 0, stream>>>(bsum, boff, nb);
    k_scan3<<<nb, 256, 0, stream>>>(boff, offs, cur, N, E);
    k_scatter_idx<<<ebl, 256, 0, stream>>>(src, dst, cur, csr_se, E);

    // layer 1
    k_nodeproj<<<1024, 128, 0, stream>>>(x, Wq1, bq1, Wk1, bk1, Wv1, bv1, Ws1, bs1,
                                         Wqe1, bqe1, qb, kvb, skipb, qeb, N);
    k_edgeattn<<<N, 64, 0, stream>>>(qb, kvb, skipb, ea, We1,
                                     offs, csr_se, qeb, h1);
    // layer 2
    k_nodeproj<<<1024, 128, 0, stream>>>(h1, Wq2, bq2, Wk2, bk2, Wv2, bv2, Ws2, bs2,
                                         Wqe2, bqe2, qb, kvb, skipb, qeb, N);
    k_edgeattn<<<N, 64, 0, stream>>>(qb, kvb, skipb, ea, We2,
                                     offs, csr_se, qeb, h2);
    // edge MLP: per-node parts hoisted; original-edge-order edge pass
    k_postproj<<<1024, 256, 0, stream>>>(h2, Wm1, bm1, hA, hC, N);
    k_mlp<<<ebl, 256, 0, stream>>>(hA, hC, ea, src, dst, Wm1, Wm2, bm2,
                                   (float*)d_out, E);
}

// Round 13
// 519.581 us; speedup vs baseline: 1.0654x; 1.0654x over previous
//
#include <hip/hip_runtime.h>
#include <hip/hip_fp16.h>
#include <math.h>

#define D128 128   // H*Ch
#define CH32 32
#define CE16 16

// ---------------- CSR build ----------------
__global__ void k_hist(const int* __restrict__ dst, int* __restrict__ deg, int E) {
    int e = blockIdx.x * blockDim.x + threadIdx.x;
    if (e < E) atomicAdd(&deg[dst[e]], 1);
}

__global__ void k_scan1(const int* __restrict__ deg, int* __restrict__ offs,
                        int* __restrict__ bsum, int N) {
    __shared__ int buf[256];
    int t = threadIdx.x;
    int i = blockIdx.x * 256 + t;
    int v = (i < N) ? deg[i] : 0;
    buf[t] = v;
    __syncthreads();
    #pragma unroll
    for (int off = 1; off < 256; off <<= 1) {
        int val = (t >= off) ? buf[t - off] : 0;
        __syncthreads();
        buf[t] += val;
        __syncthreads();
    }
    if (i < N) offs[i] = buf[t] - v;
    if (t == 255) bsum[blockIdx.x] = buf[255];
}

__global__ void k_scan2(const int* __restrict__ bsum, int* __restrict__ boff, int nb) {
    // requires nb <= 256 (N <= 65536)
    __shared__ int buf[256];
    int t = threadIdx.x;
    int v = (t < nb) ? bsum[t] : 0;
    buf[t] = v;
    __syncthreads();
    #pragma unroll
    for (int off = 1; off < 256; off <<= 1) {
        int val = (t >= off) ? buf[t - off] : 0;
        __syncthreads();
        buf[t] += val;
        __syncthreads();
    }
    if (t < nb) boff[t] = buf[t] - v;
}

__global__ void k_scan3(const int* __restrict__ boff, int* __restrict__ offs,
                        int* __restrict__ cur, int N, int E) {
    int i = blockIdx.x * blockDim.x + threadIdx.x;
    if (i < N) {
        int o = offs[i] + boff[i >> 8];
        offs[i] = o;
        cur[i] = o;
    }
    if (i == 0) offs[N] = E;
}

// ---------------- CSR scatter, split (R11 structure, restored) ----------------
// Fused scatter was write-amplification-bound (R10: 160MB WRITE vs 61MB logical).
// k_scatter_idx: small scattered writes only (4B srcb + 8B {dst,eid} = 12.8MB).
// k_gather_ea:   randomness on the READ side (L3-served), ea_csr written
//                sequentially. R13: ea_csr is fp16 (write 25.6MB, was 51.2).
__global__ void k_scatter_idx(const int* __restrict__ src, const int* __restrict__ dst,
                              int* __restrict__ cur, int* __restrict__ csr_srcb,
                              int2* __restrict__ csr_de, int E) {
    int e = blockIdx.x * blockDim.x + threadIdx.x;
    if (e < E) {
        int d = dst[e];
        int p = atomicAdd(&cur[d], 1);
        csr_srcb[p] = src[e] << 9;   // byte offset: 256 halves (512 B) per kv row
        csr_de[p] = make_int2(d, e);
    }
}

__global__ __launch_bounds__(256) void k_gather_ea(
    const float4* __restrict__ ea4, const int2* __restrict__ csr_de,
    __half* __restrict__ ea_h, int E) {
    int p = blockIdx.x * 256 + threadIdx.x;   // one edge per thread
    if (p >= E) return;
    int e = csr_de[p].y;
    float4 a0 = ea4[e * 4 + 0];
    float4 a1 = ea4[e * 4 + 1];
    float4 a2 = ea4[e * 4 + 2];
    float4 a3 = ea4[e * 4 + 3];
    __half2* o = (__half2*)(ea_h + (size_t)p * 16);
    o[0] = __floats2half2_rn(a0.x, a0.y);
    o[1] = __floats2half2_rn(a0.z, a0.w);
    o[2] = __floats2half2_rn(a1.x, a1.y);
    o[3] = __floats2half2_rn(a1.z, a1.w);
    o[4] = __floats2half2_rn(a2.x, a2.y);
    o[5] = __floats2half2_rn(a2.z, a2.w);
    o[6] = __floats2half2_rn(a3.x, a3.y);
    o[7] = __floats2half2_rn(a3.z, a3.w);
}

// ---------------- Wqe = QS * (Wq_h . We_h^T) + bias, both layers, parallel ------
// 66 blocks x 64 threads (layer x row; row 32 = bias), 32 FMA/thread.
__global__ void k_wqe(const float* __restrict__ Wq1, const float* __restrict__ bq1,
                      const float* __restrict__ We1,
                      const float* __restrict__ Wq2, const float* __restrict__ bq2,
                      const float* __restrict__ We2,
                      float* __restrict__ Wqe1, float* __restrict__ bqe1,
                      float* __restrict__ Wqe2, float* __restrict__ bqe2) {
    int t = threadIdx.x, h = t >> 4, j = t & 15;
    const float QS = 0.17677669529663687f * 1.4426950408889634f;
    int b = blockIdx.x;              // 0..65
    int layer = (b >= 33);
    int i = layer ? b - 33 : b;      // 0..32 (32 = bias row)
    const float* Wq = layer ? Wq2 : Wq1;
    const float* bq = layer ? bq2 : bq1;
    const float* We = layer ? We2 : We1;
    float* Wqe = layer ? Wqe2 : Wqe1;
    float* bqe = layer ? bqe2 : bqe1;
    const float* base = (i < 32) ? (Wq + i * D128) : bq;
    float s = 0.f;
    #pragma unroll
    for (int d = 0; d < 32; d++)
        s = fmaf(base[h * 32 + d], We[j * D128 + h * 32 + d], s);
    s *= QS;
    if (i < 32) Wqe[i * 64 + t] = s;
    else        bqe[t] = s;
}

// ---------------- node projection: fp16 q + fp16 kv + skip + qeb (fused) --------
// kv row layout (256 halves = 512 B): per 4-channel group c=ch>>2:
//   halves[8c+0..8c+3] = k[4c..4c+3], halves[8c+4..8c+7] = v[4c..4c+3]
// R13: q stored fp16 (12.8MB, was 25.6) — edgeattn reads 8B/lane.
__global__ __launch_bounds__(128) void k_nodeproj(
    const float* __restrict__ xin,
    const float* __restrict__ Wq, const float* __restrict__ bq,
    const float* __restrict__ Wk, const float* __restrict__ bk,
    const float* __restrict__ Wv, const float* __restrict__ bv,
    const float* __restrict__ Ws, const float* __restrict__ bs,
    const float* __restrict__ Wqe, const float* __restrict__ bqe,
    __half* __restrict__ qh, __half* __restrict__ kvh,
    float* __restrict__ skip, float* __restrict__ qeb, int N)
{
    int tid = threadIdx.x;      // 0..127: output column of q/k/v
    int c   = tid & 31;         // output column of skip
    int pos = ((tid >> 2) << 3) | (tid & 3);   // k half-position; v at pos+4
    float wq[32], wk[32], wv[32], ws[32];
    #pragma unroll
    for (int j = 0; j < 32; j++) {
        wq[j] = Wq[j * D128 + tid];
        wk[j] = Wk[j * D128 + tid];
        wv[j] = Wv[j * D128 + tid];
        ws[j] = Ws[j * CH32 + c];
    }
    float bqc = bq[tid], bkc = bk[tid], bvc = bv[tid], bsc = bs[c];
    __shared__ float wqeS[32][64];   // 8 KB
    __shared__ float xs[4][32];
    for (int i = tid; i < 2048; i += 128) wqeS[i >> 6][i & 63] = Wqe[i];
    float bqec = bqe[tid & 63];
    int nchunk = (N + 3) / 4;
    for (int chk = blockIdx.x; chk < nchunk; chk += gridDim.x) {
        int base = chk * 4;
        {
            int r = tid >> 5;
            int n = base + r;
            xs[r][c] = (n < N) ? xin[n * 32 + c] : 0.f;
        }
        __syncthreads();
        #pragma unroll
        for (int r = 0; r < 4; r++) {
            int n = base + r;
            if (n < N) {
                float aq = bqc, ak = bkc, av = bvc;
                #pragma unroll
                for (int j = 0; j < 32; j++) {
                    float xj = xs[r][j];
                    aq = fmaf(xj, wq[j], aq);
                    ak = fmaf(xj, wk[j], ak);
                    av = fmaf(xj, wv[j], av);
                }
                qh[(size_t)n * D128 + tid]     = __float2half_rn(aq);
                kvh[(size_t)n * 256 + pos]     = __float2half_rn(ak);  // k
                kvh[(size_t)n * 256 + pos + 4] = __float2half_rn(av);  // v
            }
        }
        {
            int r = tid >> 5;
            int n = base + r;
            if (n < N) {
                float as = bsc;
                #pragma unroll
                for (int j = 0; j < 32; j++) as = fmaf(xs[r][j], ws[j], as);
                skip[n * 32 + c] = as;
            }
        }
        {   // qeb: thread (half,c6) covers nodes {2*half, 2*half+1}, col c6
            int c6 = tid & 63;
            int r0 = (tid >> 6) << 1;
            #pragma unroll
            for (int rr = 0; rr < 2; rr++) {
                int n = base + r0 + rr;
                if (n < N) {
                    float a = bqec;
                    #pragma unroll
                    for (int j = 0; j < 32; j++)
                        a = fmaf(xs[r0 + rr][j], wqeS[j][c6], a);
                    qeb[(size_t)n * 64 + c6] = a;
                }
            }
        }
        __syncthreads();
    }
}

// ---------------- edge attention: one WAVE per node, 2 EDGES per VMEM instr -----
// Verified R9/R11 structure: lane owns 4 channels, 32 lanes/edge, 2 edges per
// VMEM instr, ping-pong pipeline, fp16 kv, CSR-streamed ea (R12's direct-ea
// read regressed: +16us/dispatch, FETCH +27MB — the sequential ea stream is
// load-bearing). R13: ea_csr and q are fp16 (32B/edge, 8B/lane).
// Algebra (validated R3): alpha = q.k[src] + qe.ea ; out = (sum p*v)/l +
// We^T(sum p*ea)/l. No-max softmax: logits provably tiny (weight scale 0.05).
__global__ __launch_bounds__(64) void k_edgeattn(
    const __half* __restrict__ qh, const __half* __restrict__ kvh,
    const float* __restrict__ skip,
    const __half* __restrict__ ea_csr, const float* __restrict__ We,
    const int* __restrict__ offs, const int* __restrict__ csr_srcb,
    const float* __restrict__ qeb, float* __restrict__ hout)
{
    int node = blockIdx.x;
    int lane = threadIdx.x;        // 0..63
    int eg   = lane >> 5;          // which edge of the pair this half handles
    int c    = lane & 31;          // 4-channel group; head = c>>3
    int g    = c & 7;              // lane within 8-lane head group
    int c4   = c << 2;             // first owned channel

    // q (fp16) pre-scaled by 1/sqrt(32) * log2(e)  (exp(x) == exp2(x*log2e))
    const float QS = 0.17677669529663687f * 1.4426950408889634f;
    float2 qraw = *(const float2*)&qh[(size_t)node * D128 + c4];  // 4 halves
    float2 q01 = __half22float2(*(const __half2*)&qraw.x);
    float2 q23 = __half22float2(*(const __half2*)&qraw.y);
    float4 qv = make_float4(q01.x * QS, q01.y * QS, q23.x * QS, q23.y * QS);

    // qe dims 2g, 2g+1 of this lane's head: precomputed (QS folded in k_wqe)
    float2 qe01 = *(const float2*)&qeb[(size_t)node * 64 + ((c >> 3) << 4) + 2 * g];
    float qe0 = qe01.x, qe1 = qe01.y;

    int s0 = offs[node], s1 = offs[node + 1];
    int deg = s1 - s0;

    float l = 0.f;
    float ac0 = 0.f, ac1 = 0.f, ac2 = 0.f, ac3 = 0.f;
    float se0 = 0.f, se1 = 0.f;

    if (deg > 0) {
        int last = s1 - 1;
        const char* kvb = (const char*)kvh;
        const char* eab = (const char*)ea_csr;
        int toff = c << 4;           // 16 bytes per 4-channel group
        int goff = g << 2;           // 4 bytes (half2) per g within 32B ea row

        // lane's edge for pair-slot p: e = s0 + 2p + eg (clamped to last)
        auto eidx = [&](int p) { return min(s0 + 2 * p + eg, last); };
        auto ldidx = [&](int p) { return csr_srcb[eidx(p)]; };
        auto ldkv  = [&](int ib) {
            return *(const float4*)(kvb + (size_t)(unsigned)ib + toff);
        };
        auto ldea  = [&](int p) {
            return *(const __half2*)(eab + ((size_t)eidx(p) << 5) + goff);
        };
        auto pair = [&](const float4& kvr, const __half2& eah, int p) {
            bool valid = (s0 + 2 * p + eg) <= last;
            float2 k01 = __half22float2(*(const __half2*)&kvr.x);
            float2 k23 = __half22float2(*(const __half2*)&kvr.y);
            float2 v01 = __half22float2(*(const __half2*)&kvr.z);
            float2 v23 = __half22float2(*(const __half2*)&kvr.w);
            float2 eav = __half22float2(eah);
            float t = fmaf(qv.y, k01.y, qv.x * k01.x);
            t = fmaf(qv.z, k23.x, t);
            t = fmaf(qv.w, k23.y, t);
            t = fmaf(qe0, eav.x, t);
            t = fmaf(qe1, eav.y, t);
            t += __shfl_xor(t, 1);
            t += __shfl_xor(t, 2);
            t += __shfl_xor(t, 4);
            float pp = valid ? __builtin_amdgcn_exp2f(t) : 0.f;
            l += pp;
            ac0 = fmaf(pp, v01.x, ac0);
            ac1 = fmaf(pp, v01.y, ac1);
            ac2 = fmaf(pp, v23.x, ac2);
            ac3 = fmaf(pp, v23.y, ac3);
            se0 = fmaf(pp, eav.x, se0);
            se1 = fmaf(pp, eav.y, se1);
        };

        // prologue: idx for pair-slots 0,1 (A) and 2,3 (B); kv/ea for A
        int iA0 = ldidx(0), iA1 = ldidx(1);
        int iB0 = ldidx(2), iB1 = ldidx(3);
        float4 kA0 = ldkv(iA0), kA1 = ldkv(iA1);
        __half2 eA0 = ldea(0),  eA1 = ldea(1);

        int p = 0;
        int nIter = (deg + 7) >> 3;     // 8 edges = 4 pair-slots per iteration
        for (int it = 0; it < nIter; ++it) {
            // issue phase-B loads (pair-slots p+2, p+3)
            float4 kB0 = ldkv(iB0), kB1 = ldkv(iB1);
            __half2 eB0 = ldea(p + 2), eB1 = ldea(p + 3);
            // prefetch indices for next phase A (slots p+4, p+5)
            iA0 = ldidx(p + 4); iA1 = ldidx(p + 5);

            // compute phase A (kv/ea issued one phase ago)
            pair(kA0, eA0, p + 0);
            pair(kA1, eA1, p + 1);

            // issue next phase-A loads (slots p+4, p+5)
            kA0 = ldkv(iA0); kA1 = ldkv(iA1);
            eA0 = ldea(p + 4); eA1 = ldea(p + 5);
            // prefetch indices for next phase B (slots p+6, p+7)
            iB0 = ldidx(p + 6); iB1 = ldidx(p + 7);

            // compute phase B
            pair(kB0, eB0, p + 2);
            pair(kB1, eB1, p + 3);

            p += 4;
        }
    }

    // epilogue: combine the two edge-halves, normalize, project sea through We,
    // mean over 4 heads, add skip, relu, store.
    l   += __shfl_xor(l, 32);
    ac0 += __shfl_xor(ac0, 32);
    ac1 += __shfl_xor(ac1, 32);
    ac2 += __shfl_xor(ac2, 32);
    ac3 += __shfl_xor(ac3, 32);
    se0 += __shfl_xor(se0, 32);
    se1 += __shfl_xor(se1, 32);

    float inv = 1.0f / (l + 1e-16f);
    float r0 = ac0 * inv, r1 = ac1 * inv, r2 = ac2 * inv, r3 = ac3 * inv;
    float sn0 = se0 * inv, sn1 = se1 * inv;

    int gb = lane & ~7;              // base lane of this 8-lane head group
    #pragma unroll
    for (int j = 0; j < 16; j++) {
        float sj = __shfl((j & 1) ? sn1 : sn0, gb | (j >> 1), 64);
        float4 wj = *(const float4*)&We[j * D128 + c4];
        r0 = fmaf(sj, wj.x, r0);
        r1 = fmaf(sj, wj.y, r1);
        r2 = fmaf(sj, wj.z, r2);
        r3 = fmaf(sj, wj.w, r3);
    }
    // head mean: lanes c, c^8, c^16, c^24 hold the same output dims for the 4 heads
    r0 += __shfl_xor(r0, 8);  r0 += __shfl_xor(r0, 16);
    r1 += __shfl_xor(r1, 8);  r1 += __shfl_xor(r1, 16);
    r2 += __shfl_xor(r2, 8);  r2 += __shfl_xor(r2, 16);
    r3 += __shfl_xor(r3, 8);  r3 += __shfl_xor(r3, 16);
    if (lane < 8) {
        const float4 sk = *(const float4*)&skip[(size_t)node * 32 + c4];
        float4 o;
        o.x = fmaxf(fmaf(0.25f, r0, sk.x), 0.f);
        o.y = fmaxf(fmaf(0.25f, r1, sk.y), 0.f);
        o.z = fmaxf(fmaf(0.25f, r2, sk.z), 0.f);
        o.w = fmaxf(fmaf(0.25f, r3, sk.w), 0.f);
        *(float4*)&hout[(size_t)node * 32 + c4] = o;
    }
}

// ---------------- hA = h@A + bm1, hC = h@C (per-node MLP pre-projection) --------
// Wm1 is [80][32]: A = rows 0..31 (h[src]), B = rows 32..47 (ea), C = rows 48..79
// (h[dst]). 80% of k_mlp's GEMM is per-NODE work repeated per edge -> hoist it.
__global__ __launch_bounds__(256) void k_postproj(
    const float* __restrict__ h, const float* __restrict__ Wm1,
    const float* __restrict__ bm1, float* __restrict__ hA,
    float* __restrict__ hC, int N) {
    __shared__ float WA[32][32], WC[32][32];   // 8 KB
    __shared__ float hs[8][32];
    int tid = threadIdx.x;
    for (int i = tid; i < 1024; i += 256) {
        WA[i >> 5][i & 31] = Wm1[i];                 // rows 0..31
        WC[i >> 5][i & 31] = Wm1[48 * 32 + i];       // rows 48..79
    }
    int col = tid & 31, r = tid >> 5;    // 8 nodes x 32 cols
    float bb = bm1[col];
    __syncthreads();
    int nchunk = (N + 7) / 8;
    for (int chk = blockIdx.x; chk < nchunk; chk += gridDim.x) {
        int n = chk * 8 + r;
        hs[r][col] = (n < N) ? h[(size_t)n * 32 + col] : 0.f;
        __syncthreads();
        if (n < N) {
            float a = bb, cc = 0.f;
            #pragma unroll
            for (int j = 0; j < 32; j++) {
                float hj = hs[r][j];
                a  = fmaf(hj, WA[j][col], a);
                cc = fmaf(hj, WC[j][col], cc);
            }
            hA[(size_t)n * 32 + col] = a;
            hC[(size_t)n * 32 + col] = cc;
        }
        __syncthreads();
    }
}

// ---------------- edge MLP: CSR order, thread per CSR position -------------------
// Iterate edges in CSR (dst-sorted) order. Consecutive threads share dst ->
// hC[dst] loads are L1-hot (only hA[src] gathers randomly). hA offset reuses
// csr_srcb (src<<9 bytes -> >>2 gives src*128B = hA row). ea_csr (fp16) is a
// sequential stream. Output scattered via csr_de.y (eid; 3.2MB, L2-absorbed).
__global__ __launch_bounds__(256) void k_mlp(
    const float* __restrict__ hA, const float* __restrict__ hC,
    const __half* __restrict__ ea_csr,
    const int* __restrict__ csr_srcb, const int2* __restrict__ csr_de,
    const float* __restrict__ Wm1, const float* __restrict__ Wm2,
    const float* __restrict__ bm2, float* __restrict__ out, int E)
{
    __shared__ float4 B4[16 * 8];     // Wm1 rows 32..47 as float4
    __shared__ float wm2L[32];
    int tid = threadIdx.x;
    const float4* Wm1B = (const float4*)(Wm1 + 32 * 32);
    for (int i = tid; i < 128; i += 256) B4[i] = Wm1B[i];
    if (tid < 32) wm2L[tid] = Wm2[tid];
    __syncthreads();

    int p = blockIdx.x * 256 + tid;
    if (p >= E) return;
    float b2 = bm2[0];
    int srcb = csr_srcb[p];
    int2 de  = csr_de[p];

    const float4* pa = (const float4*)((const char*)hA + ((size_t)(unsigned)srcb >> 2));
    const float4* pc = (const float4*)(hC + (size_t)de.x * 32);
    const float4* ev = (const float4*)(ea_csr + (size_t)p * 16);  // 32B = 2 float4

    float4 acc[8];
    #pragma unroll
    for (int i = 0; i < 8; i++) {
        float4 va = pa[i], vc = pc[i];
        acc[i] = make_float4(va.x + vc.x, va.y + vc.y, va.z + vc.z, va.w + vc.w);
    }

    auto dorow = [&](int j, float xj) {
        #pragma unroll
        for (int c4 = 0; c4 < 8; c4++) {
            float4 w = B4[j * 8 + c4];
            acc[c4].x = fmaf(xj, w.x, acc[c4].x);
            acc[c4].y = fmaf(xj, w.y, acc[c4].y);
            acc[c4].z = fmaf(xj, w.z, acc[c4].z);
            acc[c4].w = fmaf(xj, w.w, acc[c4].w);
        }
    };

    float4 raw0 = ev[0], raw1 = ev[1];   // 16 halves
    const __half2* hp0 = (const __half2*)&raw0;
    const __half2* hp1 = (const __half2*)&raw1;
    #pragma unroll
    for (int k = 0; k < 4; k++) {        // B rows 0..15: edge_attr (fp16)
        float2 ef = __half22float2(hp0[k]);
        dorow(2 * k + 0, ef.x);
        dorow(2 * k + 1, ef.y);
    }
    #pragma unroll
    for (int k = 0; k < 4; k++) {
        float2 ef = __half22float2(hp1[k]);
        dorow(8 + 2 * k + 0, ef.x);
        dorow(8 + 2 * k + 1, ef.y);
    }

    float y = b2;
    #pragma unroll
    for (int c4 = 0; c4 < 8; c4++) {
        y += fmaxf(acc[c4].x, 0.f) * wm2L[c4 * 4 + 0];
        y += fmaxf(acc[c4].y, 0.f) * wm2L[c4 * 4 + 1];
        y += fmaxf(acc[c4].z, 0.f) * wm2L[c4 * 4 + 2];
        y += fmaxf(acc[c4].w, 0.f) * wm2L[c4 * 4 + 3];
    }
    out[de.y] = y;
}

extern "C" void kernel_launch(void* const* d_in, const int* in_sizes, int n_in,
                              void* d_out, int out_size, void* d_ws, size_t ws_size,
                              hipStream_t stream)
{
    const float* x  = (const float*)d_in[0];
    const float* ea = (const float*)d_in[1];
    const int*   ei = (const int*)d_in[2];
    const int N = in_sizes[0] / 32;
    const int E = in_sizes[1] / 16;
    const int* src = ei;
    const int* dst = ei + E;

    const float *Wq1 = (const float*)d_in[3],  *bq1 = (const float*)d_in[4];
    const float *Wk1 = (const float*)d_in[5],  *bk1 = (const float*)d_in[6];
    const float *Wv1 = (const float*)d_in[7],  *bv1 = (const float*)d_in[8];
    const float *We1 = (const float*)d_in[9],  *Ws1 = (const float*)d_in[10];
    const float *bs1 = (const float*)d_in[11];
    const float *Wq2 = (const float*)d_in[12], *bq2 = (const float*)d_in[13];
    const float *Wk2 = (const float*)d_in[14], *bk2 = (const float*)d_in[15];
    const float *Wv2 = (const float*)d_in[16], *bv2 = (const float*)d_in[17];
    const float *We2 = (const float*)d_in[18], *Ws2 = (const float*)d_in[19];
    const float *bs2 = (const float*)d_in[20];
    const float *Wm1 = (const float*)d_in[21], *bm1 = (const float*)d_in[22];
    const float *Wm2 = (const float*)d_in[23], *bm2 = (const float*)d_in[24];

    char* w = (char*)d_ws;
    auto alloc = [&](size_t bytes) -> void* {
        void* p = (void*)w;
        w += (bytes + 255) & ~(size_t)255;
        return p;
    };
    int* deg      = (int*)alloc((size_t)N * 4);
    int* offs     = (int*)alloc(((size_t)N + 1) * 4);
    int* cur      = (int*)alloc((size_t)N * 4);
    int* bsum     = (int*)alloc(256 * 4);
    int* boff     = (int*)alloc(256 * 4);
    int* csr_srcb = (int*)alloc((size_t)E * 4);
    int2* csr_de  = (int2*)alloc((size_t)E * 8);
    __half* ea_csr= (__half*)alloc((size_t)E * 16 * 2);
    __half* qhb   = (__half*)alloc((size_t)N * 128 * 2);
    __half* kvb   = (__half*)alloc((size_t)N * 256 * 2);
    float* skipb  = (float*)alloc((size_t)N * 32 * 4);
    float* h1     = (float*)alloc((size_t)N * 32 * 4);
    float* h2     = (float*)alloc((size_t)N * 32 * 4);
    float* Wqe1   = (float*)alloc(32 * 64 * 4);
    float* bqe1   = (float*)alloc(64 * 4);
    float* Wqe2   = (float*)alloc(32 * 64 * 4);
    float* bqe2   = (float*)alloc(64 * 4);
    float* qeb    = (float*)alloc((size_t)N * 64 * 4);
    float* hA     = (float*)alloc((size_t)N * 32 * 4);
    float* hC     = (float*)alloc((size_t)N * 32 * 4);

    hipMemsetAsync(deg, 0, (size_t)N * 4, stream);

    int ebl = (E + 255) / 256;
    int nb  = (N + 255) / 256;   // <= 256 required by k_scan2
    k_wqe<<<66, 64, 0, stream>>>(Wq1, bq1, We1, Wq2, bq2, We2,
                                 Wqe1, bqe1, Wqe2, bqe2);
    k_hist<<<ebl, 256, 0, stream>>>(dst, deg, E);
    k_scan1<<<nb, 256, 0, stream>>>(deg, offs, bsum, N);
    k_scan2<<<1, 256, 0, stream>>>(bsum, boff, nb);
    k_scan3<<<nb, 256, 0, stream>>>(boff, offs, cur, N, E);
    k_scatter_idx<<<ebl, 256, 0, stream>>>(src, dst, cur, csr_srcb, csr_de, E);
    k_gather_ea<<<ebl, 256, 0, stream>>>((const float4*)ea, csr_de, ea_csr, E);

    // layer 1
    k_nodeproj<<<1024, 128, 0, stream>>>(x, Wq1, bq1, Wk1, bk1, Wv1, bv1, Ws1, bs1,
                                         Wqe1, bqe1, qhb, kvb, skipb, qeb, N);
    k_edgeattn<<<N, 64, 0, stream>>>(qhb, kvb, skipb, ea_csr, We1,
                                     offs, csr_srcb, qeb, h1);
    // layer 2
    k_nodeproj<<<1024, 128, 0, stream>>>(h1, Wq2, bq2, Wk2, bk2, Wv2, bv2, Ws2, bs2,
                                         Wqe2, bqe2, qhb, kvb, skipb, qeb, N);
    k_edgeattn<<<N, 64, 0, stream>>>(qhb, kvb, skipb, ea_csr, We2,
                                     offs, csr_srcb, qeb, h2);
    // edge MLP: per-node parts hoisted; CSR-ordered edge pass
    k_postproj<<<1024, 256, 0, stream>>>(h2, Wm1, bm1, hA, hC, N);
    k_mlp<<<ebl, 256, 0, stream>>>(hA, hC, ea_csr, csr_srcb, csr_de,
                                   Wm1, Wm2, bm2, (float*)d_out, E);
}

// Round 14
// 510.956 us; speedup vs baseline: 1.0834x; 1.0169x over previous
//
#include <hip/hip_runtime.h>
#include <hip/hip_fp16.h>
#include <math.h>

#define D128 128   // H*Ch
#define CH32 32
#define CE16 16

// ---------------- CSR build ----------------
__global__ void k_hist(const int* __restrict__ dst, int* __restrict__ deg, int E) {
    int e = blockIdx.x * blockDim.x + threadIdx.x;
    if (e < E) atomicAdd(&deg[dst[e]], 1);
}

__global__ void k_scan1(const int* __restrict__ deg, int* __restrict__ offs,
                        int* __restrict__ bsum, int N) {
    __shared__ int buf[256];
    int t = threadIdx.x;
    int i = blockIdx.x * 256 + t;
    int v = (i < N) ? deg[i] : 0;
    buf[t] = v;
    __syncthreads();
    #pragma unroll
    for (int off = 1; off < 256; off <<= 1) {
        int val = (t >= off) ? buf[t - off] : 0;
        __syncthreads();
        buf[t] += val;
        __syncthreads();
    }
    if (i < N) offs[i] = buf[t] - v;
    if (t == 255) bsum[blockIdx.x] = buf[255];
}

__global__ void k_scan2(const int* __restrict__ bsum, int* __restrict__ boff, int nb) {
    // requires nb <= 256 (N <= 65536)
    __shared__ int buf[256];
    int t = threadIdx.x;
    int v = (t < nb) ? bsum[t] : 0;
    buf[t] = v;
    __syncthreads();
    #pragma unroll
    for (int off = 1; off < 256; off <<= 1) {
        int val = (t >= off) ? buf[t - off] : 0;
        __syncthreads();
        buf[t] += val;
        __syncthreads();
    }
    if (t < nb) boff[t] = buf[t] - v;
}

__global__ void k_scan3(const int* __restrict__ boff, int* __restrict__ offs,
                        int* __restrict__ cur, int N, int E) {
    int i = blockIdx.x * blockDim.x + threadIdx.x;
    if (i < N) {
        int o = offs[i] + boff[i >> 8];
        offs[i] = o;
        cur[i] = o;
    }
    if (i == 0) offs[N] = E;
}

// ---------------- CSR scatter, split (R11 structure) ----------------
// Fused scatter was write-amplification-bound (R10: 160MB WRITE vs 61MB logical).
// k_scatter_idx: small scattered writes only (4B srcb + 8B {dst,eid} = 12.8MB).
// k_gather_ea:   randomness on the READ side (L3-served), ea_csr (fp16) written
//                sequentially. R14: back to 4-threads-per-edge (quad-coalesced
//                16B reads, packed 8B stores) — R13's 1-thread form did 4
//                strided loads + 8 scalar 4B stores.
__global__ void k_scatter_idx(const int* __restrict__ src, const int* __restrict__ dst,
                              int* __restrict__ cur, int* __restrict__ csr_srcb,
                              int2* __restrict__ csr_de, int E) {
    int e = blockIdx.x * blockDim.x + threadIdx.x;
    if (e < E) {
        int d = dst[e];
        int p = atomicAdd(&cur[d], 1);
        csr_srcb[p] = src[e] << 9;   // byte offset: 256 halves (512 B) per kv row
        csr_de[p] = make_int2(d, e);
    }
}

__global__ __launch_bounds__(256) void k_gather_ea(
    const float4* __restrict__ ea4, const int2* __restrict__ csr_de,
    __half* __restrict__ ea_h, int E) {
    int idx = blockIdx.x * 256 + threadIdx.x;   // one float4 per thread
    int p = idx >> 2, q = idx & 3;
    if (p < E) {
        int e = csr_de[p].y;                    // quad-broadcast load
        float4 v = ea4[e * 4 + q];              // 16B, quad-coalesced (64B/edge)
        union { __half2 h[2]; float2 f; } u;
        u.h[0] = __floats2half2_rn(v.x, v.y);
        u.h[1] = __floats2half2_rn(v.z, v.w);
        *(float2*)(ea_h + (size_t)p * 16 + q * 4) = u.f;  // 8B, fully coalesced
    }
}

// ---------------- Wqe = QS * (Wq_h . We_h^T) + bias, both layers, parallel ------
// 66 blocks x 64 threads (layer x row; row 32 = bias), 32 FMA/thread.
__global__ void k_wqe(const float* __restrict__ Wq1, const float* __restrict__ bq1,
                      const float* __restrict__ We1,
                      const float* __restrict__ Wq2, const float* __restrict__ bq2,
                      const float* __restrict__ We2,
                      float* __restrict__ Wqe1, float* __restrict__ bqe1,
                      float* __restrict__ Wqe2, float* __restrict__ bqe2) {
    int t = threadIdx.x, h = t >> 4, j = t & 15;
    const float QS = 0.17677669529663687f * 1.4426950408889634f;
    int b = blockIdx.x;              // 0..65
    int layer = (b >= 33);
    int i = layer ? b - 33 : b;      // 0..32 (32 = bias row)
    const float* Wq = layer ? Wq2 : Wq1;
    const float* bq = layer ? bq2 : bq1;
    const float* We = layer ? We2 : We1;
    float* Wqe = layer ? Wqe2 : Wqe1;
    float* bqe = layer ? bqe2 : bqe1;
    const float* base = (i < 32) ? (Wq + i * D128) : bq;
    float s = 0.f;
    #pragma unroll
    for (int d = 0; d < 32; d++)
        s = fmaf(base[h * 32 + d], We[j * D128 + h * 32 + d], s);
    s *= QS;
    if (i < 32) Wqe[i * 64 + t] = s;
    else        bqe[t] = s;
}

// ---------------- node projection: fp16 q + fp16 kv + skip + qeb (fused) --------
// kv row layout (256 halves = 512 B): per 4-channel group c=ch>>2:
//   halves[8c+0..8c+3] = k[4c..4c+3], halves[8c+4..8c+7] = v[4c..4c+3]
__global__ __launch_bounds__(128) void k_nodeproj(
    const float* __restrict__ xin,
    const float* __restrict__ Wq, const float* __restrict__ bq,
    const float* __restrict__ Wk, const float* __restrict__ bk,
    const float* __restrict__ Wv, const float* __restrict__ bv,
    const float* __restrict__ Ws, const float* __restrict__ bs,
    const float* __restrict__ Wqe, const float* __restrict__ bqe,
    __half* __restrict__ qh, __half* __restrict__ kvh,
    float* __restrict__ skip, float* __restrict__ qeb, int N)
{
    int tid = threadIdx.x;      // 0..127: output column of q/k/v
    int c   = tid & 31;         // output column of skip
    int pos = ((tid >> 2) << 3) | (tid & 3);   // k half-position; v at pos+4
    float wq[32], wk[32], wv[32], ws[32];
    #pragma unroll
    for (int j = 0; j < 32; j++) {
        wq[j] = Wq[j * D128 + tid];
        wk[j] = Wk[j * D128 + tid];
        wv[j] = Wv[j * D128 + tid];
        ws[j] = Ws[j * CH32 + c];
    }
    float bqc = bq[tid], bkc = bk[tid], bvc = bv[tid], bsc = bs[c];
    __shared__ float wqeS[32][64];   // 8 KB
    __shared__ float xs[4][32];
    for (int i = tid; i < 2048; i += 128) wqeS[i >> 6][i & 63] = Wqe[i];
    float bqec = bqe[tid & 63];
    int nchunk = (N + 3) / 4;
    for (int chk = blockIdx.x; chk < nchunk; chk += gridDim.x) {
        int base = chk * 4;
        {
            int r = tid >> 5;
            int n = base + r;
            xs[r][c] = (n < N) ? xin[n * 32 + c] : 0.f;
        }
        __syncthreads();
        #pragma unroll
        for (int r = 0; r < 4; r++) {
            int n = base + r;
            if (n < N) {
                float aq = bqc, ak = bkc, av = bvc;
                #pragma unroll
                for (int j = 0; j < 32; j++) {
                    float xj = xs[r][j];
                    aq = fmaf(xj, wq[j], aq);
                    ak = fmaf(xj, wk[j], ak);
                    av = fmaf(xj, wv[j], av);
                }
                qh[(size_t)n * D128 + tid]     = __float2half_rn(aq);
                kvh[(size_t)n * 256 + pos]     = __float2half_rn(ak);  // k
                kvh[(size_t)n * 256 + pos + 4] = __float2half_rn(av);  // v
            }
        }
        {
            int r = tid >> 5;
            int n = base + r;
            if (n < N) {
                float as = bsc;
                #pragma unroll
                for (int j = 0; j < 32; j++) as = fmaf(xs[r][j], ws[j], as);
                skip[n * 32 + c] = as;
            }
        }
        {   // qeb: thread (half,c6) covers nodes {2*half, 2*half+1}, col c6
            int c6 = tid & 63;
            int r0 = (tid >> 6) << 1;
            #pragma unroll
            for (int rr = 0; rr < 2; rr++) {
                int n = base + r0 + rr;
                if (n < N) {
                    float a = bqec;
                    #pragma unroll
                    for (int j = 0; j < 32; j++)
                        a = fmaf(xs[r0 + rr][j], wqeS[j][c6], a);
                    qeb[(size_t)n * 64 + c6] = a;
                }
            }
        }
        __syncthreads();
    }
}

// ---------------- edge attention: one WAVE per node, 2 EDGES per VMEM instr -----
// Verified R9/R11/R13 structure: lane owns 4 channels, 32 lanes/edge, 2 edges
// per VMEM instr, ping-pong pipeline, fp16 kv/q/ea (CSR-streamed ea — R12's
// direct-ea read regressed). FROZEN this round.
// Algebra (validated R3): alpha = q.k[src] + qe.ea ; out = (sum p*v)/l +
// We^T(sum p*ea)/l. No-max softmax: logits provably tiny (weight scale 0.05).
__global__ __launch_bounds__(64) void k_edgeattn(
    const __half* __restrict__ qh, const __half* __restrict__ kvh,
    const float* __restrict__ skip,
    const __half* __restrict__ ea_csr, const float* __restrict__ We,
    const int* __restrict__ offs, const int* __restrict__ csr_srcb,
    const float* __restrict__ qeb, float* __restrict__ hout)
{
    int node = blockIdx.x;
    int lane = threadIdx.x;        // 0..63
    int eg   = lane >> 5;          // which edge of the pair this half handles
    int c    = lane & 31;          // 4-channel group; head = c>>3
    int g    = c & 7;              // lane within 8-lane head group
    int c4   = c << 2;             // first owned channel

    // q (fp16) pre-scaled by 1/sqrt(32) * log2(e)  (exp(x) == exp2(x*log2e))
    const float QS = 0.17677669529663687f * 1.4426950408889634f;
    float2 qraw = *(const float2*)&qh[(size_t)node * D128 + c4];  // 4 halves
    float2 q01 = __half22float2(*(const __half2*)&qraw.x);
    float2 q23 = __half22float2(*(const __half2*)&qraw.y);
    float4 qv = make_float4(q01.x * QS, q01.y * QS, q23.x * QS, q23.y * QS);

    // qe dims 2g, 2g+1 of this lane's head: precomputed (QS folded in k_wqe)
    float2 qe01 = *(const float2*)&qeb[(size_t)node * 64 + ((c >> 3) << 4) + 2 * g];
    float qe0 = qe01.x, qe1 = qe01.y;

    int s0 = offs[node], s1 = offs[node + 1];
    int deg = s1 - s0;

    float l = 0.f;
    float ac0 = 0.f, ac1 = 0.f, ac2 = 0.f, ac3 = 0.f;
    float se0 = 0.f, se1 = 0.f;

    if (deg > 0) {
        int last = s1 - 1;
        const char* kvb = (const char*)kvh;
        const char* eab = (const char*)ea_csr;
        int toff = c << 4;           // 16 bytes per 4-channel group
        int goff = g << 2;           // 4 bytes (half2) per g within 32B ea row

        // lane's edge for pair-slot p: e = s0 + 2p + eg (clamped to last)
        auto eidx = [&](int p) { return min(s0 + 2 * p + eg, last); };
        auto ldidx = [&](int p) { return csr_srcb[eidx(p)]; };
        auto ldkv  = [&](int ib) {
            return *(const float4*)(kvb + (size_t)(unsigned)ib + toff);
        };
        auto ldea  = [&](int p) {
            return *(const __half2*)(eab + ((size_t)eidx(p) << 5) + goff);
        };
        auto pair = [&](const float4& kvr, const __half2& eah, int p) {
            bool valid = (s0 + 2 * p + eg) <= last;
            float2 k01 = __half22float2(*(const __half2*)&kvr.x);
            float2 k23 = __half22float2(*(const __half2*)&kvr.y);
            float2 v01 = __half22float2(*(const __half2*)&kvr.z);
            float2 v23 = __half22float2(*(const __half2*)&kvr.w);
            float2 eav = __half22float2(eah);
            float t = fmaf(qv.y, k01.y, qv.x * k01.x);
            t = fmaf(qv.z, k23.x, t);
            t = fmaf(qv.w, k23.y, t);
            t = fmaf(qe0, eav.x, t);
            t = fmaf(qe1, eav.y, t);
            t += __shfl_xor(t, 1);
            t += __shfl_xor(t, 2);
            t += __shfl_xor(t, 4);
            float pp = valid ? __builtin_amdgcn_exp2f(t) : 0.f;
            l += pp;
            ac0 = fmaf(pp, v01.x, ac0);
            ac1 = fmaf(pp, v01.y, ac1);
            ac2 = fmaf(pp, v23.x, ac2);
            ac3 = fmaf(pp, v23.y, ac3);
            se0 = fmaf(pp, eav.x, se0);
            se1 = fmaf(pp, eav.y, se1);
        };

        // prologue: idx for pair-slots 0,1 (A) and 2,3 (B); kv/ea for A
        int iA0 = ldidx(0), iA1 = ldidx(1);
        int iB0 = ldidx(2), iB1 = ldidx(3);
        float4 kA0 = ldkv(iA0), kA1 = ldkv(iA1);
        __half2 eA0 = ldea(0),  eA1 = ldea(1);

        int p = 0;
        int nIter = (deg + 7) >> 3;     // 8 edges = 4 pair-slots per iteration
        for (int it = 0; it < nIter; ++it) {
            // issue phase-B loads (pair-slots p+2, p+3)
            float4 kB0 = ldkv(iB0), kB1 = ldkv(iB1);
            __half2 eB0 = ldea(p + 2), eB1 = ldea(p + 3);
            // prefetch indices for next phase A (slots p+4, p+5)
            iA0 = ldidx(p + 4); iA1 = ldidx(p + 5);

            // compute phase A (kv/ea issued one phase ago)
            pair(kA0, eA0, p + 0);
            pair(kA1, eA1, p + 1);

            // issue next phase-A loads (slots p+4, p+5)
            kA0 = ldkv(iA0); kA1 = ldkv(iA1);
            eA0 = ldea(p + 4); eA1 = ldea(p + 5);
            // prefetch indices for next phase B (slots p+6, p+7)
            iB0 = ldidx(p + 6); iB1 = ldidx(p + 7);

            // compute phase B
            pair(kB0, eB0, p + 2);
            pair(kB1, eB1, p + 3);

            p += 4;
        }
    }

    // epilogue: combine the two edge-halves, normalize, project sea through We,
    // mean over 4 heads, add skip, relu, store.
    l   += __shfl_xor(l, 32);
    ac0 += __shfl_xor(ac0, 32);
    ac1 += __shfl_xor(ac1, 32);
    ac2 += __shfl_xor(ac2, 32);
    ac3 += __shfl_xor(ac3, 32);
    se0 += __shfl_xor(se0, 32);
    se1 += __shfl_xor(se1, 32);

    float inv = 1.0f / (l + 1e-16f);
    float r0 = ac0 * inv, r1 = ac1 * inv, r2 = ac2 * inv, r3 = ac3 * inv;
    float sn0 = se0 * inv, sn1 = se1 * inv;

    int gb = lane & ~7;              // base lane of this 8-lane head group
    #pragma unroll
    for (int j = 0; j < 16; j++) {
        float sj = __shfl((j & 1) ? sn1 : sn0, gb | (j >> 1), 64);
        float4 wj = *(const float4*)&We[j * D128 + c4];
        r0 = fmaf(sj, wj.x, r0);
        r1 = fmaf(sj, wj.y, r1);
        r2 = fmaf(sj, wj.z, r2);
        r3 = fmaf(sj, wj.w, r3);
    }
    // head mean: lanes c, c^8, c^16, c^24 hold the same output dims for the 4 heads
    r0 += __shfl_xor(r0, 8);  r0 += __shfl_xor(r0, 16);
    r1 += __shfl_xor(r1, 8);  r1 += __shfl_xor(r1, 16);
    r2 += __shfl_xor(r2, 8);  r2 += __shfl_xor(r2, 16);
    r3 += __shfl_xor(r3, 8);  r3 += __shfl_xor(r3, 16);
    if (lane < 8) {
        const float4 sk = *(const float4*)&skip[(size_t)node * 32 + c4];
        float4 o;
        o.x = fmaxf(fmaf(0.25f, r0, sk.x), 0.f);
        o.y = fmaxf(fmaf(0.25f, r1, sk.y), 0.f);
        o.z = fmaxf(fmaf(0.25f, r2, sk.z), 0.f);
        o.w = fmaxf(fmaf(0.25f, r3, sk.w), 0.f);
        *(float4*)&hout[(size_t)node * 32 + c4] = o;
    }
}

// ---------------- hA = h@A + bm1, hC = h@C (per-node MLP pre-projection) --------
// Wm1 is [80][32]: A = rows 0..31 (h[src]), B = rows 32..47 (ea), C = rows 48..79
// (h[dst]). R14: hA/hC stored fp16 — halves k_mlp's dominant random gather
// (102MB -> 51MB). Error through relu·wm2 (scale 0.05) ~1e-5, negligible.
__global__ __launch_bounds__(256) void k_postproj(
    const float* __restrict__ h, const float* __restrict__ Wm1,
    const float* __restrict__ bm1, __half* __restrict__ hA,
    __half* __restrict__ hC, int N) {
    __shared__ float WA[32][32], WC[32][32];   // 8 KB
    __shared__ float hs[8][32];
    int tid = threadIdx.x;
    for (int i = tid; i < 1024; i += 256) {
        WA[i >> 5][i & 31] = Wm1[i];                 // rows 0..31
        WC[i >> 5][i & 31] = Wm1[48 * 32 + i];       // rows 48..79
    }
    int col = tid & 31, r = tid >> 5;    // 8 nodes x 32 cols
    float bb = bm1[col];
    __syncthreads();
    int nchunk = (N + 7) / 8;
    for (int chk = blockIdx.x; chk < nchunk; chk += gridDim.x) {
        int n = chk * 8 + r;
        hs[r][col] = (n < N) ? h[(size_t)n * 32 + col] : 0.f;
        __syncthreads();
        if (n < N) {
            float a = bb, cc = 0.f;
            #pragma unroll
            for (int j = 0; j < 32; j++) {
                float hj = hs[r][j];
                a  = fmaf(hj, WA[j][col], a);
                cc = fmaf(hj, WC[j][col], cc);
            }
            hA[(size_t)n * 32 + col] = __float2half_rn(a);
            hC[(size_t)n * 32 + col] = __float2half_rn(cc);
        }
        __syncthreads();
    }
}

// ---------------- edge MLP: CSR order, thread per CSR position -------------------
// Iterate edges in CSR (dst-sorted) order. Consecutive threads share dst ->
// hC[dst] loads are L1-hot (only hA[src] gathers randomly, now fp16 = 64B/edge).
// hA offset: csr_srcb = src<<9 -> src*64B = srcb>>3 bytes. ea_csr (fp16) is a
// sequential stream. Output scattered via csr_de.y (eid; 3.2MB, L2-absorbed).
__global__ __launch_bounds__(256) void k_mlp(
    const __half* __restrict__ hA, const __half* __restrict__ hC,
    const __half* __restrict__ ea_csr,
    const int* __restrict__ csr_srcb, const int2* __restrict__ csr_de,
    const float* __restrict__ Wm1, const float* __restrict__ Wm2,
    const float* __restrict__ bm2, float* __restrict__ out, int E)
{
    __shared__ float4 B4[16 * 8];     // Wm1 rows 32..47 as float4
    __shared__ float wm2L[32];
    int tid = threadIdx.x;
    const float4* Wm1B = (const float4*)(Wm1 + 32 * 32);
    for (int i = tid; i < 128; i += 256) B4[i] = Wm1B[i];
    if (tid < 32) wm2L[tid] = Wm2[tid];
    __syncthreads();

    int p = blockIdx.x * 256 + tid;
    if (p >= E) return;
    float b2 = bm2[0];
    int srcb = csr_srcb[p];
    int2 de  = csr_de[p];

    const float4* pa = (const float4*)((const char*)hA + ((size_t)(unsigned)srcb >> 3));
    const float4* pc = (const float4*)((const char*)hC + (size_t)de.x * 64);
    const float4* ev = (const float4*)(ea_csr + (size_t)p * 16);  // 32B = 2 float4

    // z = hA[src] + hC[dst] (both fp16, 32 halves = 4 float4 loads each)
    float zc[32];
    #pragma unroll
    for (int i = 0; i < 4; i++) {
        float4 ra = pa[i], rc = pc[i];
        const __half2* ha = (const __half2*)&ra;
        const __half2* hc = (const __half2*)&rc;
        #pragma unroll
        for (int k = 0; k < 4; k++) {
            float2 fa = __half22float2(ha[k]);
            float2 fc = __half22float2(hc[k]);
            zc[i * 8 + k * 2 + 0] = fa.x + fc.x;
            zc[i * 8 + k * 2 + 1] = fa.y + fc.y;
        }
    }

    auto dorow = [&](int j, float xj) {
        #pragma unroll
        for (int c4 = 0; c4 < 8; c4++) {
            float4 w = B4[j * 8 + c4];
            zc[c4 * 4 + 0] = fmaf(xj, w.x, zc[c4 * 4 + 0]);
            zc[c4 * 4 + 1] = fmaf(xj, w.y, zc[c4 * 4 + 1]);
            zc[c4 * 4 + 2] = fmaf(xj, w.z, zc[c4 * 4 + 2]);
            zc[c4 * 4 + 3] = fmaf(xj, w.w, zc[c4 * 4 + 3]);
        }
    };

    float4 raw0 = ev[0], raw1 = ev[1];   // 16 halves of edge_attr
    const __half2* hp0 = (const __half2*)&raw0;
    const __half2* hp1 = (const __half2*)&raw1;
    #pragma unroll
    for (int k = 0; k < 4; k++) {
        float2 ef = __half22float2(hp0[k]);
        dorow(2 * k + 0, ef.x);
        dorow(2 * k + 1, ef.y);
    }
    #pragma unroll
    for (int k = 0; k < 4; k++) {
        float2 ef = __half22float2(hp1[k]);
        dorow(8 + 2 * k + 0, ef.x);
        dorow(8 + 2 * k + 1, ef.y);
    }

    float y = b2;
    #pragma unroll
    for (int c = 0; c < 32; c++) y += fmaxf(zc[c], 0.f) * wm2L[c];
    out[de.y] = y;
}

extern "C" void kernel_launch(void* const* d_in, const int* in_sizes, int n_in,
                              void* d_out, int out_size, void* d_ws, size_t ws_size,
                              hipStream_t stream)
{
    const float* x  = (const float*)d_in[0];
    const float* ea = (const float*)d_in[1];
    const int*   ei = (const int*)d_in[2];
    const int N = in_sizes[0] / 32;
    const int E = in_sizes[1] / 16;
    const int* src = ei;
    const int* dst = ei + E;

    const float *Wq1 = (const float*)d_in[3],  *bq1 = (const float*)d_in[4];
    const float *Wk1 = (const float*)d_in[5],  *bk1 = (const float*)d_in[6];
    const float *Wv1 = (const float*)d_in[7],  *bv1 = (const float*)d_in[8];
    const float *We1 = (const float*)d_in[9],  *Ws1 = (const float*)d_in[10];
    const float *bs1 = (const float*)d_in[11];
    const float *Wq2 = (const float*)d_in[12], *bq2 = (const float*)d_in[13];
    const float *Wk2 = (const float*)d_in[14], *bk2 = (const float*)d_in[15];
    const float *Wv2 = (const float*)d_in[16], *bv2 = (const float*)d_in[17];
    const float *We2 = (const float*)d_in[18], *Ws2 = (const float*)d_in[19];
    const float *bs2 = (const float*)d_in[20];
    const float *Wm1 = (const float*)d_in[21], *bm1 = (const float*)d_in[22];
    const float *Wm2 = (const float*)d_in[23], *bm2 = (const float*)d_in[24];

    char* w = (char*)d_ws;
    auto alloc = [&](size_t bytes) -> void* {
        void* p = (void*)w;
        w += (bytes + 255) & ~(size_t)255;
        return p;
    };
    int* deg      = (int*)alloc((size_t)N * 4);
    int* offs     = (int*)alloc(((size_t)N + 1) * 4);
    int* cur      = (int*)alloc((size_t)N * 4);
    int* bsum     = (int*)alloc(256 * 4);
    int* boff     = (int*)alloc(256 * 4);
    int* csr_srcb = (int*)alloc((size_t)E * 4);
    int2* csr_de  = (int2*)alloc((size_t)E * 8);
    __half* ea_csr= (__half*)alloc((size_t)E * 16 * 2);
    __half* qhb   = (__half*)alloc((size_t)N * 128 * 2);
    __half* kvb   = (__half*)alloc((size_t)N * 256 * 2);
    float* skipb  = (float*)alloc((size_t)N * 32 * 4);
    float* h1     = (float*)alloc((size_t)N * 32 * 4);
    float* h2     = (float*)alloc((size_t)N * 32 * 4);
    float* Wqe1   = (float*)alloc(32 * 64 * 4);
    float* bqe1   = (float*)alloc(64 * 4);
    float* Wqe2   = (float*)alloc(32 * 64 * 4);
    float* bqe2   = (float*)alloc(64 * 4);
    float* qeb    = (float*)alloc((size_t)N * 64 * 4);
    __half* hA    = (__half*)alloc((size_t)N * 32 * 2);
    __half* hC    = (__half*)alloc((size_t)N * 32 * 2);

    hipMemsetAsync(deg, 0, (size_t)N * 4, stream);

    int ebl = (E + 255) / 256;
    int nb  = (N + 255) / 256;   // <= 256 required by k_scan2
    k_wqe<<<66, 64, 0, stream>>>(Wq1, bq1, We1, Wq2, bq2, We2,
                                 Wqe1, bqe1, Wqe2, bqe2);
    k_hist<<<ebl, 256, 0, stream>>>(dst, deg, E);
    k_scan1<<<nb, 256, 0, stream>>>(deg, offs, bsum, N);
    k_scan2<<<1, 256, 0, stream>>>(bsum, boff, nb);
    k_scan3<<<nb, 256, 0, stream>>>(boff, offs, cur, N, E);
    k_scatter_idx<<<ebl, 256, 0, stream>>>(src, dst, cur, csr_srcb, csr_de, E);
    k_gather_ea<<<(E * 4 + 255) / 256, 256, 0, stream>>>(
        (const float4*)ea, csr_de, ea_csr, E);

    // layer 1
    k_nodeproj<<<1024, 128, 0, stream>>>(x, Wq1, bq1, Wk1, bk1, Wv1, bv1, Ws1, bs1,
                                         Wqe1, bqe1, qhb, kvb, skipb, qeb, N);
    k_edgeattn<<<N, 64, 0, stream>>>(qhb, kvb, skipb, ea_csr, We1,
                                     offs, csr_srcb, qeb, h1);
    // layer 2
    k_nodeproj<<<1024, 128, 0, stream>>>(h1, Wq2, bq2, Wk2, bk2, Wv2, bv2, Ws2, bs2,
                                         Wqe2, bqe2, qhb, kvb, skipb, qeb, N);
    k_edgeattn<<<N, 64, 0, stream>>>(qhb, kvb, skipb, ea_csr, We2,
                                     offs, csr_srcb, qeb, h2);
    // edge MLP: per-node parts hoisted (fp16); CSR-ordered edge pass
    k_postproj<<<1024, 256, 0, stream>>>(h2, Wm1, bm1, hA, hC, N);
    k_mlp<<<ebl, 256, 0, stream>>>(hA, hC, ea_csr, csr_srcb, csr_de,
                                   Wm1, Wm2, bm2, (float*)d_out, E);
}

// Round 15
// 508.470 us; speedup vs baseline: 1.0887x; 1.0049x over previous
//
#include <hip/hip_runtime.h>
#include <hip/hip_fp16.h>
#include <math.h>

#define D128 128   // H*Ch
#define CH32 32
#define CE16 16

// ---------------- fused init: Wqe precompute (blocks 0-65) + degree hist -------
// R15: two independent small kernels fused to cut a launch boundary.
__global__ __launch_bounds__(256) void k_init(
    const float* __restrict__ Wq1, const float* __restrict__ bq1,
    const float* __restrict__ We1,
    const float* __restrict__ Wq2, const float* __restrict__ bq2,
    const float* __restrict__ We2,
    float* __restrict__ Wqe1, float* __restrict__ bqe1,
    float* __restrict__ Wqe2, float* __restrict__ bqe2,
    const int* __restrict__ dst, int* __restrict__ deg, int E)
{
    if (blockIdx.x < 66) {
        int t = threadIdx.x;
        if (t < 64) {
            int h = t >> 4, j = t & 15;
            const float QS = 0.17677669529663687f * 1.4426950408889634f;
            int b = blockIdx.x;              // 0..65
            int layer = (b >= 33);
            int i = layer ? b - 33 : b;      // 0..32 (32 = bias row)
            const float* Wq = layer ? Wq2 : Wq1;
            const float* bq = layer ? bq2 : bq1;
            const float* We = layer ? We2 : We1;
            float* Wqe = layer ? Wqe2 : Wqe1;
            float* bqe = layer ? bqe2 : bqe1;
            const float* base = (i < 32) ? (Wq + i * D128) : bq;
            float s = 0.f;
            #pragma unroll
            for (int d = 0; d < 32; d++)
                s = fmaf(base[h * 32 + d], We[j * D128 + h * 32 + d], s);
            s *= QS;
            if (i < 32) Wqe[i * 64 + t] = s;
            else        bqe[t] = s;
        }
    } else {
        int e = (blockIdx.x - 66) * 256 + threadIdx.x;
        if (e < E) atomicAdd(&deg[dst[e]], 1);
    }
}

__global__ void k_scan1(const int* __restrict__ deg, int* __restrict__ offs,
                        int* __restrict__ bsum, int N) {
    __shared__ int buf[256];
    int t = threadIdx.x;
    int i = blockIdx.x * 256 + t;
    int v = (i < N) ? deg[i] : 0;
    buf[t] = v;
    __syncthreads();
    #pragma unroll
    for (int off = 1; off < 256; off <<= 1) {
        int val = (t >= off) ? buf[t - off] : 0;
        __syncthreads();
        buf[t] += val;
        __syncthreads();
    }
    if (i < N) offs[i] = buf[t] - v;
    if (t == 255) bsum[blockIdx.x] = buf[255];
}

__global__ void k_scan2(const int* __restrict__ bsum, int* __restrict__ boff, int nb) {
    // requires nb <= 256 (N <= 65536)
    __shared__ int buf[256];
    int t = threadIdx.x;
    int v = (t < nb) ? bsum[t] : 0;
    buf[t] = v;
    __syncthreads();
    #pragma unroll
    for (int off = 1; off < 256; off <<= 1) {
        int val = (t >= off) ? buf[t - off] : 0;
        __syncthreads();
        buf[t] += val;
        __syncthreads();
    }
    if (t < nb) boff[t] = buf[t] - v;
}

__global__ void k_scan3(const int* __restrict__ boff, int* __restrict__ offs,
                        int* __restrict__ cur, int N, int E) {
    int i = blockIdx.x * blockDim.x + threadIdx.x;
    if (i < N) {
        int o = offs[i] + boff[i >> 8];
        offs[i] = o;
        cur[i] = o;
    }
    if (i == 0) offs[N] = E;
}

// ---------------- CSR scatter: small scattered index writes only ----------------
__global__ void k_scatter_idx(const int* __restrict__ src, const int* __restrict__ dst,
                              int* __restrict__ cur, int* __restrict__ csr_srcb,
                              int2* __restrict__ csr_de, int E) {
    int e = blockIdx.x * blockDim.x + threadIdx.x;
    if (e < E) {
        int d = dst[e];
        int p = atomicAdd(&cur[d], 1);
        csr_srcb[p] = src[e] << 9;   // byte offset: 256 halves (512 B) per kv row
        csr_de[p] = make_int2(d, e);
    }
}

// ---------------- node projection body (shared by standalone + fused kernels) ---
// fp16 q + fp16 interleaved kv + fp32 skip + fp32 qeb. kv row layout (256 halves):
// per 4-channel group c: halves[8c..8c+3]=k[4c..], halves[8c+4..8c+7]=v[4c..].
__device__ __forceinline__ void nodeproj_body(
    const float* __restrict__ xin,
    const float* __restrict__ Wq, const float* __restrict__ bq,
    const float* __restrict__ Wk, const float* __restrict__ bk,
    const float* __restrict__ Wv, const float* __restrict__ bv,
    const float* __restrict__ Ws, const float* __restrict__ bs,
    const float* __restrict__ Wqe, const float* __restrict__ bqe,
    __half* __restrict__ qh, __half* __restrict__ kvh,
    float* __restrict__ skip, float* __restrict__ qeb, int N,
    int bid, int nblocks)
{
    int tid = threadIdx.x;      // 0..127: output column of q/k/v
    int c   = tid & 31;         // output column of skip
    int pos = ((tid >> 2) << 3) | (tid & 3);   // k half-position; v at pos+4
    float wq[32], wk[32], wv[32], ws[32];
    #pragma unroll
    for (int j = 0; j < 32; j++) {
        wq[j] = Wq[j * D128 + tid];
        wk[j] = Wk[j * D128 + tid];
        wv[j] = Wv[j * D128 + tid];
        ws[j] = Ws[j * CH32 + c];
    }
    float bqc = bq[tid], bkc = bk[tid], bvc = bv[tid], bsc = bs[c];
    __shared__ float wqeS[32][64];   // 8 KB
    __shared__ float xs[4][32];
    for (int i = tid; i < 2048; i += 128) wqeS[i >> 6][i & 63] = Wqe[i];
    float bqec = bqe[tid & 63];
    int nchunk = (N + 3) / 4;
    for (int chk = bid; chk < nchunk; chk += nblocks) {
        int base = chk * 4;
        {
            int r = tid >> 5;
            int n = base + r;
            xs[r][c] = (n < N) ? xin[n * 32 + c] : 0.f;
        }
        __syncthreads();
        #pragma unroll
        for (int r = 0; r < 4; r++) {
            int n = base + r;
            if (n < N) {
                float aq = bqc, ak = bkc, av = bvc;
                #pragma unroll
                for (int j = 0; j < 32; j++) {
                    float xj = xs[r][j];
                    aq = fmaf(xj, wq[j], aq);
                    ak = fmaf(xj, wk[j], ak);
                    av = fmaf(xj, wv[j], av);
                }
                qh[(size_t)n * D128 + tid]     = __float2half_rn(aq);
                kvh[(size_t)n * 256 + pos]     = __float2half_rn(ak);  // k
                kvh[(size_t)n * 256 + pos + 4] = __float2half_rn(av);  // v
            }
        }
        {
            int r = tid >> 5;
            int n = base + r;
            if (n < N) {
                float as = bsc;
                #pragma unroll
                for (int j = 0; j < 32; j++) as = fmaf(xs[r][j], ws[j], as);
                skip[n * 32 + c] = as;
            }
        }
        {   // qeb: thread (half,c6) covers nodes {2*half, 2*half+1}, col c6
            int c6 = tid & 63;
            int r0 = (tid >> 6) << 1;
            #pragma unroll
            for (int rr = 0; rr < 2; rr++) {
                int n = base + r0 + rr;
                if (n < N) {
                    float a = bqec;
                    #pragma unroll
                    for (int j = 0; j < 32; j++)
                        a = fmaf(xs[r0 + rr][j], wqeS[j][c6], a);
                    qeb[(size_t)n * 64 + c6] = a;
                }
            }
        }
        __syncthreads();
    }
}

// standalone node projection (layer 2)
__global__ __launch_bounds__(128) void k_nodeproj(
    const float* __restrict__ xin,
    const float* __restrict__ Wq, const float* __restrict__ bq,
    const float* __restrict__ Wk, const float* __restrict__ bk,
    const float* __restrict__ Wv, const float* __restrict__ bv,
    const float* __restrict__ Ws, const float* __restrict__ bs,
    const float* __restrict__ Wqe, const float* __restrict__ bqe,
    __half* __restrict__ qh, __half* __restrict__ kvh,
    float* __restrict__ skip, float* __restrict__ qeb, int N)
{
    nodeproj_body(xin, Wq, bq, Wk, bk, Wv, bv, Ws, bs, Wqe, bqe,
                  qh, kvh, skip, qeb, N, blockIdx.x, gridDim.x);
}

// fused: layer-1 node projection (blocks 0-1023) + ea CSR gather (rest).
// R15: the two are independent (x -> proj; csr_de -> gather) and both
// memory-bound — co-scheduling overlaps them (~max instead of sum).
__global__ __launch_bounds__(128) void k_np_gea(
    const float* __restrict__ xin,
    const float* __restrict__ Wq, const float* __restrict__ bq,
    const float* __restrict__ Wk, const float* __restrict__ bk,
    const float* __restrict__ Wv, const float* __restrict__ bv,
    const float* __restrict__ Ws, const float* __restrict__ bs,
    const float* __restrict__ Wqe, const float* __restrict__ bqe,
    __half* __restrict__ qh, __half* __restrict__ kvh,
    float* __restrict__ skip, float* __restrict__ qeb, int N,
    const float4* __restrict__ ea4, const int2* __restrict__ csr_de,
    __half* __restrict__ ea_h, int E)
{
    if (blockIdx.x < 1024) {
        nodeproj_body(xin, Wq, bq, Wk, bk, Wv, bv, Ws, bs, Wqe, bqe,
                      qh, kvh, skip, qeb, N, blockIdx.x, 1024);
    } else {
        int base = (blockIdx.x - 1024) * 256 + threadIdx.x;
        #pragma unroll
        for (int s = 0; s < 2; s++) {
            int idx = base + s * 128;
            int p = idx >> 2, q = idx & 3;
            if (p < E) {
                int e = csr_de[p].y;            // quad-broadcast load
                float4 v = ea4[e * 4 + q];      // 16B, quad-coalesced (64B/edge)
                union { __half2 h[2]; float2 f; } u;
                u.h[0] = __floats2half2_rn(v.x, v.y);
                u.h[1] = __floats2half2_rn(v.z, v.w);
                *(float2*)(ea_h + (size_t)p * 16 + q * 4) = u.f;  // coalesced
            }
        }
    }
}

// ---------------- edge attention: one WAVE per node, 2 EDGES per VMEM instr -----
// Verified R9/R11/R13 structure (FROZEN): lane owns 4 channels, 32 lanes/edge,
// 2 edges per VMEM instr, ping-pong pipeline, fp16 kv/q/ea (CSR-streamed ea).
// R15: template<PP>. PP=1 (layer 2) fuses the k_postproj matvec into the
// epilogue: after xor8/xor16 head-mean every lane holds a replicated copy of
// the node's h2 channel-quad (lanes c, c^8, c^16, c^24 identical), so the
// 32x64 matvec = 32 shfl + 32 L1-hot Wm1 loads + 32 FMA per lane; writes
// hA (=h2@A+bm1) / hC (=h2@C) in fp16 directly; h2 is never materialized.
// Algebra (validated R3): alpha = q.k[src] + qe.ea ; out = (sum p*v)/l +
// We^T(sum p*ea)/l. No-max softmax: logits provably tiny (weight scale 0.05).
template<int PP>
__global__ __launch_bounds__(64) void k_edgeattn(
    const __half* __restrict__ qh, const __half* __restrict__ kvh,
    const float* __restrict__ skip,
    const __half* __restrict__ ea_csr, const float* __restrict__ We,
    const int* __restrict__ offs, const int* __restrict__ csr_srcb,
    const float* __restrict__ qeb, float* __restrict__ hout,
    const float* __restrict__ Wm1, const float* __restrict__ bm1,
    __half* __restrict__ hA, __half* __restrict__ hC)
{
    int node = blockIdx.x;
    int lane = threadIdx.x;        // 0..63
    int eg   = lane >> 5;          // which edge of the pair this half handles
    int c    = lane & 31;          // 4-channel group; head = c>>3
    int g    = c & 7;              // lane within 8-lane head group
    int c4   = c << 2;             // first owned channel

    // q (fp16) pre-scaled by 1/sqrt(32) * log2(e)  (exp(x) == exp2(x*log2e))
    const float QS = 0.17677669529663687f * 1.4426950408889634f;
    float2 qraw = *(const float2*)&qh[(size_t)node * D128 + c4];  // 4 halves
    float2 q01 = __half22float2(*(const __half2*)&qraw.x);
    float2 q23 = __half22float2(*(const __half2*)&qraw.y);
    float4 qv = make_float4(q01.x * QS, q01.y * QS, q23.x * QS, q23.y * QS);

    // qe dims 2g, 2g+1 of this lane's head: precomputed (QS folded in k_init)
    float2 qe01 = *(const float2*)&qeb[(size_t)node * 64 + ((c >> 3) << 4) + 2 * g];
    float qe0 = qe01.x, qe1 = qe01.y;

    int s0 = offs[node], s1 = offs[node + 1];
    int deg = s1 - s0;

    float l = 0.f;
    float ac0 = 0.f, ac1 = 0.f, ac2 = 0.f, ac3 = 0.f;
    float se0 = 0.f, se1 = 0.f;

    if (deg > 0) {
        int last = s1 - 1;
        const char* kvb = (const char*)kvh;
        const char* eab = (const char*)ea_csr;
        int toff = c << 4;           // 16 bytes per 4-channel group
        int goff = g << 2;           // 4 bytes (half2) per g within 32B ea row

        // lane's edge for pair-slot p: e = s0 + 2p + eg (clamped to last)
        auto eidx = [&](int p) { return min(s0 + 2 * p + eg, last); };
        auto ldidx = [&](int p) { return csr_srcb[eidx(p)]; };
        auto ldkv  = [&](int ib) {
            return *(const float4*)(kvb + (size_t)(unsigned)ib + toff);
        };
        auto ldea  = [&](int p) {
            return *(const __half2*)(eab + ((size_t)eidx(p) << 5) + goff);
        };
        auto pair = [&](const float4& kvr, const __half2& eah, int p) {
            bool valid = (s0 + 2 * p + eg) <= last;
            float2 k01 = __half22float2(*(const __half2*)&kvr.x);
            float2 k23 = __half22float2(*(const __half2*)&kvr.y);
            float2 v01 = __half22float2(*(const __half2*)&kvr.z);
            float2 v23 = __half22float2(*(const __half2*)&kvr.w);
            float2 eav = __half22float2(eah);
            float t = fmaf(qv.y, k01.y, qv.x * k01.x);
            t = fmaf(qv.z, k23.x, t);
            t = fmaf(qv.w, k23.y, t);
            t = fmaf(qe0, eav.x, t);
            t = fmaf(qe1, eav.y, t);
            t += __shfl_xor(t, 1);
            t += __shfl_xor(t, 2);
            t += __shfl_xor(t, 4);
            float pp = valid ? __builtin_amdgcn_exp2f(t) : 0.f;
            l += pp;
            ac0 = fmaf(pp, v01.x, ac0);
            ac1 = fmaf(pp, v01.y, ac1);
            ac2 = fmaf(pp, v23.x, ac2);
            ac3 = fmaf(pp, v23.y, ac3);
            se0 = fmaf(pp, eav.x, se0);
            se1 = fmaf(pp, eav.y, se1);
        };

        // prologue: idx for pair-slots 0,1 (A) and 2,3 (B); kv/ea for A
        int iA0 = ldidx(0), iA1 = ldidx(1);
        int iB0 = ldidx(2), iB1 = ldidx(3);
        float4 kA0 = ldkv(iA0), kA1 = ldkv(iA1);
        __half2 eA0 = ldea(0),  eA1 = ldea(1);

        int p = 0;
        int nIter = (deg + 7) >> 3;     // 8 edges = 4 pair-slots per iteration
        for (int it = 0; it < nIter; ++it) {
            // issue phase-B loads (pair-slots p+2, p+3)
            float4 kB0 = ldkv(iB0), kB1 = ldkv(iB1);
            __half2 eB0 = ldea(p + 2), eB1 = ldea(p + 3);
            // prefetch indices for next phase A (slots p+4, p+5)
            iA0 = ldidx(p + 4); iA1 = ldidx(p + 5);

            // compute phase A (kv/ea issued one phase ago)
            pair(kA0, eA0, p + 0);
            pair(kA1, eA1, p + 1);

            // issue next phase-A loads (slots p+4, p+5)
            kA0 = ldkv(iA0); kA1 = ldkv(iA1);
            eA0 = ldea(p + 4); eA1 = ldea(p + 5);
            // prefetch indices for next phase B (slots p+6, p+7)
            iB0 = ldidx(p + 6); iB1 = ldidx(p + 7);

            // compute phase B
            pair(kB0, eB0, p + 2);
            pair(kB1, eB1, p + 3);

            p += 4;
        }
    }

    // epilogue: combine the two edge-halves, normalize, project sea through We,
    // mean over 4 heads, add skip, relu.
    l   += __shfl_xor(l, 32);
    ac0 += __shfl_xor(ac0, 32);
    ac1 += __shfl_xor(ac1, 32);
    ac2 += __shfl_xor(ac2, 32);
    ac3 += __shfl_xor(ac3, 32);
    se0 += __shfl_xor(se0, 32);
    se1 += __shfl_xor(se1, 32);

    float inv = 1.0f / (l + 1e-16f);
    float r0 = ac0 * inv, r1 = ac1 * inv, r2 = ac2 * inv, r3 = ac3 * inv;
    float sn0 = se0 * inv, sn1 = se1 * inv;

    int gb = lane & ~7;              // base lane of this 8-lane head group
    #pragma unroll
    for (int j = 0; j < 16; j++) {
        float sj = __shfl((j & 1) ? sn1 : sn0, gb | (j >> 1), 64);
        float4 wj = *(const float4*)&We[j * D128 + c4];
        r0 = fmaf(sj, wj.x, r0);
        r1 = fmaf(sj, wj.y, r1);
        r2 = fmaf(sj, wj.z, r2);
        r3 = fmaf(sj, wj.w, r3);
    }
    // head mean: after xor8+xor16, lanes c, c^8, c^16, c^24 all hold the sums
    // for within-head channel quad (c&7)*4 .. +3
    r0 += __shfl_xor(r0, 8);  r0 += __shfl_xor(r0, 16);
    r1 += __shfl_xor(r1, 8);  r1 += __shfl_xor(r1, 16);
    r2 += __shfl_xor(r2, 8);  r2 += __shfl_xor(r2, 16);
    r3 += __shfl_xor(r3, 8);  r3 += __shfl_xor(r3, 16);

    if constexpr (PP == 0) {
        if (lane < 8) {
            const float4 sk = *(const float4*)&skip[(size_t)node * 32 + c4];
            float4 o;
            o.x = fmaxf(fmaf(0.25f, r0, sk.x), 0.f);
            o.y = fmaxf(fmaf(0.25f, r1, sk.y), 0.f);
            o.z = fmaxf(fmaf(0.25f, r2, sk.z), 0.f);
            o.w = fmaxf(fmaf(0.25f, r3, sk.w), 0.f);
            *(float4*)&hout[(size_t)node * 32 + c4] = o;
        }
    } else {
        // all lanes hold the quad for channels 4*(c&7)..+3 — compute h2 quad
        int a8 = (c & 7) << 2;
        const float4 sk = *(const float4*)&skip[(size_t)node * 32 + a8];
        float4 o;
        o.x = fmaxf(fmaf(0.25f, r0, sk.x), 0.f);
        o.y = fmaxf(fmaf(0.25f, r1, sk.y), 0.f);
        o.z = fmaxf(fmaf(0.25f, r2, sk.z), 0.f);
        o.w = fmaxf(fmaf(0.25f, r3, sk.w), 0.f);
        // fused postproj matvec: lanes 0-31 -> hA col, lanes 32-63 -> hC col
        int col = lane & 31;
        const float* Wb = (lane < 32) ? (Wm1 + col) : (Wm1 + 48 * 32 + col);
        float acc = (lane < 32) ? bm1[col] : 0.f;
        #pragma unroll
        for (int a = 0; a < 8; a++) {
            float hx = __shfl(o.x, a, 64);
            float hy = __shfl(o.y, a, 64);
            float hz = __shfl(o.z, a, 64);
            float hw = __shfl(o.w, a, 64);
            acc = fmaf(hx, Wb[(4 * a + 0) * 32], acc);
            acc = fmaf(hy, Wb[(4 * a + 1) * 32], acc);
            acc = fmaf(hz, Wb[(4 * a + 2) * 32], acc);
            acc = fmaf(hw, Wb[(4 * a + 3) * 32], acc);
        }
        __half* dstp = (lane < 32) ? hA : hC;
        dstp[(size_t)node * 32 + col] = __float2half_rn(acc);
    }
}

// ---------------- edge MLP: CSR order, thread per CSR position -------------------
// hC[dst] loads L1-hot (CSR order); hA[src] random fp16 gather (64B/edge);
// ea_csr (fp16) sequential; output scattered via csr_de.y.
__global__ __launch_bounds__(256) void k_mlp(
    const __half* __restrict__ hA, const __half* __restrict__ hC,
    const __half* __restrict__ ea_csr,
    const int* __restrict__ csr_srcb, const int2* __restrict__ csr_de,
    const float* __restrict__ Wm1, const float* __restrict__ Wm2,
    const float* __restrict__ bm2, float* __restrict__ out, int E)
{
    __shared__ float4 B4[16 * 8];     // Wm1 rows 32..47 as float4
    __shared__ float wm2L[32];
    int tid = threadIdx.x;
    const float4* Wm1B = (const float4*)(Wm1 + 32 * 32);
    for (int i = tid; i < 128; i += 256) B4[i] = Wm1B[i];
    if (tid < 32) wm2L[tid] = Wm2[tid];
    __syncthreads();

    int p = blockIdx.x * 256 + tid;
    if (p >= E) return;
    float b2 = bm2[0];
    int srcb = csr_srcb[p];
    int2 de  = csr_de[p];

    const float4* pa = (const float4*)((const char*)hA + ((size_t)(unsigned)srcb >> 3));
    const float4* pc = (const float4*)((const char*)hC + (size_t)de.x * 64);
    const float4* ev = (const float4*)(ea_csr + (size_t)p * 16);  // 32B = 2 float4

    // z = hA[src] + hC[dst] (both fp16, 32 halves = 4 float4 loads each)
    float zc[32];
    #pragma unroll
    for (int i = 0; i < 4; i++) {
        float4 ra = pa[i], rc = pc[i];
        const __half2* ha = (const __half2*)&ra;
        const __half2* hc = (const __half2*)&rc;
        #pragma unroll
        for (int k = 0; k < 4; k++) {
            float2 fa = __half22float2(ha[k]);
            float2 fc = __half22float2(hc[k]);
            zc[i * 8 + k * 2 + 0] = fa.x + fc.x;
            zc[i * 8 + k * 2 + 1] = fa.y + fc.y;
        }
    }

    auto dorow = [&](int j, float xj) {
        #pragma unroll
        for (int c4 = 0; c4 < 8; c4++) {
            float4 w = B4[j * 8 + c4];
            zc[c4 * 4 + 0] = fmaf(xj, w.x, zc[c4 * 4 + 0]);
            zc[c4 * 4 + 1] = fmaf(xj, w.y, zc[c4 * 4 + 1]);
            zc[c4 * 4 + 2] = fmaf(xj, w.z, zc[c4 * 4 + 2]);
            zc[c4 * 4 + 3] = fmaf(xj, w.w, zc[c4 * 4 + 3]);
        }
    };

    float4 raw0 = ev[0], raw1 = ev[1];   // 16 halves of edge_attr
    const __half2* hp0 = (const __half2*)&raw0;
    const __half2* hp1 = (const __half2*)&raw1;
    #pragma unroll
    for (int k = 0; k < 4; k++) {
        float2 ef = __half22float2(hp0[k]);
        dorow(2 * k + 0, ef.x);
        dorow(2 * k + 1, ef.y);
    }
    #pragma unroll
    for (int k = 0; k < 4; k++) {
        float2 ef = __half22float2(hp1[k]);
        dorow(8 + 2 * k + 0, ef.x);
        dorow(8 + 2 * k + 1, ef.y);
    }

    float y = b2;
    #pragma unroll
    for (int c = 0; c < 32; c++) y += fmaxf(zc[c], 0.f) * wm2L[c];
    out[de.y] = y;
}

extern "C" void kernel_launch(void* const* d_in, const int* in_sizes, int n_in,
                              void* d_out, int out_size, void* d_ws, size_t ws_size,
                              hipStream_t stream)
{
    const float* x  = (const float*)d_in[0];
    const float* ea = (const float*)d_in[1];
    const int*   ei = (const int*)d_in[2];
    const int N = in_sizes[0] / 32;
    const int E = in_sizes[1] / 16;
    const int* src = ei;
    const int* dst = ei + E;

    const float *Wq1 = (const float*)d_in[3],  *bq1 = (const float*)d_in[4];
    const float *Wk1 = (const float*)d_in[5],  *bk1 = (const float*)d_in[6];
    const float *Wv1 = (const float*)d_in[7],  *bv1 = (const float*)d_in[8];
    const float *We1 = (const float*)d_in[9],  *Ws1 = (const float*)d_in[10];
    const float *bs1 = (const float*)d_in[11];
    const float *Wq2 = (const float*)d_in[12], *bq2 = (const float*)d_in[13];
    const float *Wk2 = (const float*)d_in[14], *bk2 = (const float*)d_in[15];
    const float *Wv2 = (const float*)d_in[16], *bv2 = (const float*)d_in[17];
    const float *We2 = (const float*)d_in[18], *Ws2 = (const float*)d_in[19];
    const float *bs2 = (const float*)d_in[20];
    const float *Wm1 = (const float*)d_in[21], *bm1 = (const float*)d_in[22];
    const float *Wm2 = (const float*)d_in[23], *bm2 = (const float*)d_in[24];

    char* w = (char*)d_ws;
    auto alloc = [&](size_t bytes) -> void* {
        void* p = (void*)w;
        w += (bytes + 255) & ~(size_t)255;
        return p;
    };
    int* deg      = (int*)alloc((size_t)N * 4);
    int* offs     = (int*)alloc(((size_t)N + 1) * 4);
    int* cur      = (int*)alloc((size_t)N * 4);
    int* bsum     = (int*)alloc(256 * 4);
    int* boff     = (int*)alloc(256 * 4);
    int* csr_srcb = (int*)alloc((size_t)E * 4);
    int2* csr_de  = (int2*)alloc((size_t)E * 8);
    __half* ea_csr= (__half*)alloc((size_t)E * 16 * 2);
    __half* qhb   = (__half*)alloc((size_t)N * 128 * 2);
    __half* kvb   = (__half*)alloc((size_t)N * 256 * 2);
    float* skipb  = (float*)alloc((size_t)N * 32 * 4);
    float* h1     = (float*)alloc((size_t)N * 32 * 4);
    float* Wqe1   = (float*)alloc(32 * 64 * 4);
    float* bqe1   = (float*)alloc(64 * 4);
    float* Wqe2   = (float*)alloc(32 * 64 * 4);
    float* bqe2   = (float*)alloc(64 * 4);
    float* qeb    = (float*)alloc((size_t)N * 64 * 4);
    __half* hA    = (__half*)alloc((size_t)N * 32 * 2);
    __half* hC    = (__half*)alloc((size_t)N * 32 * 2);

    hipMemsetAsync(deg, 0, (size_t)N * 4, stream);

    int ebl = (E + 255) / 256;
    int nb  = (N + 255) / 256;   // <= 256 required by k_scan2
    int gb  = (E * 4 + 255) / 256;   // gather_ea blocks (256 items each)

    k_init<<<66 + ebl, 256, 0, stream>>>(Wq1, bq1, We1, Wq2, bq2, We2,
                                         Wqe1, bqe1, Wqe2, bqe2, dst, deg, E);
    k_scan1<<<nb, 256, 0, stream>>>(deg, offs, bsum, N);
    k_scan2<<<1, 256, 0, stream>>>(bsum, boff, nb);
    k_scan3<<<nb, 256, 0, stream>>>(boff, offs, cur, N, E);
    k_scatter_idx<<<ebl, 256, 0, stream>>>(src, dst, cur, csr_srcb, csr_de, E);

    // layer 1 node projection fused with ea gather (independent, both mem-bound)
    k_np_gea<<<1024 + gb, 128, 0, stream>>>(
        x, Wq1, bq1, Wk1, bk1, Wv1, bv1, Ws1, bs1, Wqe1, bqe1,
        qhb, kvb, skipb, qeb, N, (const float4*)ea, csr_de, ea_csr, E);
    k_edgeattn<0><<<N, 64, 0, stream>>>(qhb, kvb, skipb, ea_csr, We1,
                                        offs, csr_srcb, qeb, h1,
                                        Wm1, bm1, hA, hC);
    // layer 2
    k_nodeproj<<<1024, 128, 0, stream>>>(h1, Wq2, bq2, Wk2, bk2, Wv2, bv2, Ws2, bs2,
                                         Wqe2, bqe2, qhb, kvb, skipb, qeb, N);
    k_edgeattn<1><<<N, 64, 0, stream>>>(qhb, kvb, skipb, ea_csr, We2,
                                        offs, csr_srcb, qeb, h1,
                                        Wm1, bm1, hA, hC);
    // edge MLP (postproj fused into edgeattn<1>'s epilogue)
    k_mlp<<<ebl, 256, 0, stream>>>(hA, hC, ea_csr, csr_srcb, csr_de,
                                   Wm1, Wm2, bm2, (float*)d_out, E);
}